// Round 1
// baseline (1107.247 us; speedup 1.0000x reference)
//
#include <hip/hip_runtime.h>
#include <hip/hip_bf16.h>
#include <cstdint>
#include <cstddef>

#define B_ 2048
#define S_ 168

// ---------- helpers ----------
typedef _Float16 h2_t __attribute__((ext_vector_type(2)));

__device__ __forceinline__ float dot2h(unsigned a, unsigned b, float c){
    h2_t av = __builtin_bit_cast(h2_t, a);
    h2_t bv = __builtin_bit_cast(h2_t, b);
    return __builtin_amdgcn_fdot2(av, bv, c, false);
}
__device__ __forceinline__ unsigned pack_h2f(float a, float b){
    h2_t v; v.x = (_Float16)a; v.y = (_Float16)b;
    return __builtin_bit_cast(unsigned, v);
}
__device__ __forceinline__ float fast_exp(float x){      // e^x
    return __builtin_amdgcn_exp2f(x * 1.44269504088896340736f);
}
__device__ __forceinline__ float fast_sigmoid(float x){  // 1/(1+e^-x)
    return __builtin_amdgcn_rcpf(1.0f + fast_exp(-x));
}
__device__ __forceinline__ float fast_tanh(float x){     // 1 - 2/(e^2x+1)
    return 1.0f - 2.0f * __builtin_amdgcn_rcpf(1.0f + fast_exp(2.0f * x));
}

// ---------- kernel 1: attention over stations ----------
// softmax is shift-invariant: local_emb@Wl + b_attn are per-row constants -> dropped.
__global__ void nbst_attn(const float* __restrict__ sn, const float* __restrict__ Wn,
                          const float* __restrict__ bn, const float* __restrict__ Wa,
                          float* __restrict__ attnO){
    __shared__ float WnL[64*16];
    __shared__ float WsL[64];
    __shared__ float bnL[64];
    const int tid = threadIdx.x;
    for (int e = tid; e < 1024; e += 256) WnL[e] = Wn[e];
    if (tid < 64){ WsL[tid] = Wa[64 + tid]; bnL[tid] = bn[tid]; }
    __syncthreads();
    const int wv = tid >> 6, l = tid & 63;
    const int b = blockIdx.x * 4 + wv;
    const float* xp = sn + ((size_t)b * 64 + l) * 16;
    float x[16];
    #pragma unroll
    for (int k = 0; k < 16; ++k) x[k] = xp[k];
    float e_i = 0.f;
    for (int h = 0; h < 64; ++h){
        float acc = bnL[h];
        #pragma unroll
        for (int k = 0; k < 16; ++k) acc += x[k] * WnL[h*16 + k];
        e_i += fast_tanh(acc) * WsL[h];
    }
    float m = e_i;
    #pragma unroll
    for (int s = 32; s >= 1; s >>= 1) m = fmaxf(m, __shfl_xor(m, s));
    float p = fast_exp(e_i - m);
    float ssum = p;
    #pragma unroll
    for (int s = 32; s >= 1; s >>= 1) ssum += __shfl_xor(ssum, s);
    attnO[(size_t)b*64 + l] = p * __builtin_amdgcn_rcpf(ssum);
}

// ---------- kernel 2: fused sfe-MLP + GRU layer 0 ----------
// LDS layout (u32 units)
#define OW_RZ   0        // [96][128] fp16-pairs : k-pairs x (r|z gate cols)
#define OW_XN   12288    // [64][64]
#define OW_HN   16384    // [32][64]
#define OW_D1   18432    // [18][32]
#define OW_D2   19008    // [16][64]
#define O_CAT   20032    // [18][8]
#define O_H1    20176    // [16][8]
#define O_ACAT  20304    // [96][8]  (0..31 fA, 32..63 sfe, 64..95 h)
#define O_GACC  21072    // float [4][8][64]
#define O_EMB   23120    // float [264]
#define LDS2_U32 23384

__global__ __launch_bounds__(256, 1)
void nbst_gru0(const float* __restrict__ sf, const int* __restrict__ se,
               const float* __restrict__ e0, const float* __restrict__ e1,
               const float* __restrict__ e2, const float* __restrict__ e3,
               const float* __restrict__ e4,
               const float* __restrict__ Wd1, const float* __restrict__ bd1g,
               const float* __restrict__ Wd2, const float* __restrict__ bd2g,
               const float* __restrict__ Wih0, const float* __restrict__ Whh0,
               const float* __restrict__ bih0, const float* __restrict__ bhh0,
               const float* __restrict__ attnI,
               unsigned* __restrict__ out0g, float* __restrict__ hf0g)
{
    extern __shared__ unsigned sm[];
    float* smF = reinterpret_cast<float*>(sm);
    const int tid = threadIdx.x;
    const int b0 = blockIdx.x * 8;

    // ---- stage fp16-packed weights ----
    for (int e = tid; e < 96*128; e += 256){
        int kk = e >> 7, g = e & 127;
        float w0, w1;
        if (kk < 64){ w0 = Wih0[g*128 + 2*kk];     w1 = Wih0[g*128 + 2*kk + 1]; }
        else { int k2 = kk - 64; w0 = Whh0[g*64 + 2*k2]; w1 = Whh0[g*64 + 2*k2 + 1]; }
        sm[OW_RZ + e] = pack_h2f(w0, w1);
    }
    for (int e = tid; e < 64*64; e += 256){
        int kk = e >> 6, n = e & 63;
        sm[OW_XN + e] = pack_h2f(Wih0[(128+n)*128 + 2*kk], Wih0[(128+n)*128 + 2*kk + 1]);
    }
    for (int e = tid; e < 32*64; e += 256){
        int kk = e >> 6, n = e & 63;
        sm[OW_HN + e] = pack_h2f(Whh0[(128+n)*64 + 2*kk], Whh0[(128+n)*64 + 2*kk + 1]);
    }
    for (int e = tid; e < 18*32; e += 256){
        int kk = e >> 5, o = e & 31;
        sm[OW_D1 + e] = pack_h2f(Wd1[o*36 + 2*kk], Wd1[o*36 + 2*kk + 1]);
    }
    for (int e = tid; e < 16*64; e += 256){
        int kk = e >> 6, o = e & 63;
        sm[OW_D2 + e] = pack_h2f(Wd2[o*32 + 2*kk], Wd2[o*32 + 2*kk + 1]);
    }
    for (int e = tid; e < 260; e += 256){
        float v;
        if (e < 48)       v = e0[e];
        else if (e < 88)  v = e1[e-48];
        else if (e < 136) v = e2[e-88];
        else if (e < 164) v = e3[e-136];
        else              v = e4[e-164];
        smF[O_EMB + e] = v;
    }
    sm[O_ACAT + 64*8 + tid] = 0u;   // h(0)=0 (entries [512,768))

    // ---- per-thread persistent state ----
    const int np = tid & 31, r = tid >> 5;
    const int wv = tid >> 6, l = tid & 63, gs = l & 15, rs = l >> 4;
    const size_t rowbase = (size_t)(b0 + r) * S_;

    const float aA0 = attnI[(size_t)(b0+r)*64 + 2*np];
    const float aA1 = attnI[(size_t)(b0+r)*64 + 2*np + 1];
    const float bd1r = bd1g[np];
    const float bd2_0 = bd2g[2*np], bd2_1 = bd2g[2*np+1];
    const float br0 = bih0[2*np]      + bhh0[2*np];
    const float br1 = bih0[2*np+1]    + bhh0[2*np+1];
    const float bz0 = bih0[64+2*np]   + bhh0[64+2*np];
    const float bz1 = bih0[64+2*np+1] + bhh0[64+2*np+1];
    const float bxn0 = bih0[128+2*np], bxn1 = bih0[128+2*np+1];
    const float bhn0 = bhh0[128+2*np], bhn1 = bhh0[128+2*np+1];
    float hr0 = 0.f, hr1 = 0.f;

    // cat prefetch (t=0): globals only; emb table lookups stay in LDS at use time
    const int kkc = np;
    float v0r = 0.f, v1r = 0.f; int idxr = 0;
    if (kkc < 8){
        v0r = sf[rowbase*16 + 2*kkc]; v1r = sf[rowbase*16 + 2*kkc + 1];
    } else if (kkc < 18){
        int ebl = (2*kkc - 16) >> 2;
        idxr = se[rowbase*5 + ebl];
    }
    const int toffs[5] = {0, 48, 88, 136, 164};
    __syncthreads();

    for (int t = 0; t < S_; ++t){
        // ---- CAT: write packed cat(36) ----
        if (kkc < 18){
            float c0, c1;
            if (kkc < 8){ c0 = v0r; c1 = v1r; }
            else {
                int j = 2*kkc - 16;
                int ebl = j >> 2, d0 = j & 3;
                int idx = idxr - (ebl >= 2 ? 1 : 0);
                c0 = smF[O_EMB + toffs[ebl] + idx*4 + d0];
                c1 = smF[O_EMB + toffs[ebl] + idx*4 + d0 + 1];
            }
            sm[O_CAT + kkc*8 + r] = pack_h2f(c0, c1);
        }
        { // prefetch t+1 globals (latency hidden across the step)
            int tn = (t + 1 < S_) ? t + 1 : t;
            if (kkc < 8){
                v0r = sf[(rowbase + tn)*16 + 2*kkc]; v1r = sf[(rowbase + tn)*16 + 2*kkc + 1];
            } else if (kkc < 18){
                int ebl = (2*kkc - 16) >> 2;
                idxr = se[(rowbase + tn)*5 + ebl];
            }
        }
        __syncthreads();
        // ---- H1: 32 outs x 8 rows, K=36 ----
        {
            float acc = bd1r;
            #pragma unroll
            for (int kk = 0; kk < 18; ++kk)
                acc = dot2h(sm[O_CAT + kk*8 + r], sm[OW_D1 + kk*32 + np], acc);
            float th = fast_tanh(acc);
            float partner = __shfl_xor(th, 1);
            if ((np & 1) == 0) sm[O_H1 + (np>>1)*8 + r] = pack_h2f(th, partner);
        }
        __syncthreads();
        // ---- SFE: 64 outs x 8 rows, K=32; writes fA and sfe panels ----
        {
            float a0 = bd2_0, a1 = bd2_1;
            #pragma unroll
            for (int kk = 0; kk < 16; ++kk){
                unsigned hh = sm[O_H1 + kk*8 + r];
                a0 = dot2h(hh, sm[OW_D2 + kk*64 + 2*np],     a0);
                a1 = dot2h(hh, sm[OW_D2 + kk*64 + 2*np + 1], a1);
            }
            float s0v = fast_tanh(a0), s1v = fast_tanh(a1);
            sm[O_ACAT + (32+np)*8 + r] = pack_h2f(s0v, s1v);
            sm[O_ACAT + np*8 + r]      = pack_h2f(aA0*s0v, aA1*s1v);
        }
        __syncthreads();
        // ---- DOT: rz / xn / hn gate pre-activations ----
        {
            float a00=0,a01=0,a10=0,a11=0,a20=0,a21=0,a30=0,a31=0;
            int wbase, wstr, colo, abase2, nkk;
            if (wv == 0)      { wbase = OW_RZ; wstr = 128; colo = 0;  abase2 = O_ACAT;        nkk = 96; }
            else if (wv == 1) { wbase = OW_RZ; wstr = 128; colo = 64; abase2 = O_ACAT;        nkk = 96; }
            else if (wv == 2) { wbase = OW_XN; wstr = 64;  colo = 0;  abase2 = O_ACAT;        nkk = 64; }
            else              { wbase = OW_HN; wstr = 64;  colo = 0;  abase2 = O_ACAT + 64*8; nkk = 32; }
            const unsigned* wp = sm + wbase + colo + 4*gs;
            const unsigned* ap = sm + abase2 + rs;
            #pragma unroll 4
            for (int kk = 0; kk < nkk; ++kk){
                unsigned aa0 = ap[kk*8], aa1 = ap[kk*8 + 4];
                uint4 wq = *reinterpret_cast<const uint4*>(wp + kk*wstr);
                a00 = dot2h(aa0, wq.x, a00); a01 = dot2h(aa1, wq.x, a01);
                a10 = dot2h(aa0, wq.y, a10); a11 = dot2h(aa1, wq.y, a11);
                a20 = dot2h(aa0, wq.z, a20); a21 = dot2h(aa1, wq.z, a21);
                a30 = dot2h(aa0, wq.w, a30); a31 = dot2h(aa1, wq.w, a31);
            }
            *reinterpret_cast<float4*>(smF + O_GACC + (wv*8 + rs)*64 + 4*gs)     = make_float4(a00, a10, a20, a30);
            *reinterpret_cast<float4*>(smF + O_GACC + (wv*8 + rs + 4)*64 + 4*gs) = make_float4(a01, a11, a21, a31);
        }
        __syncthreads();
        // ---- GATE: combine, activations, state update ----
        {
            const float* gF = smF + O_GACC;
            float2 rp = *reinterpret_cast<const float2*>(gF + (0*8 + r)*64 + 2*np);
            float2 zp = *reinterpret_cast<const float2*>(gF + (1*8 + r)*64 + 2*np);
            float2 xv = *reinterpret_cast<const float2*>(gF + (2*8 + r)*64 + 2*np);
            float2 hv = *reinterpret_cast<const float2*>(gF + (3*8 + r)*64 + 2*np);
            float rg0 = fast_sigmoid(rp.x + br0), rg1 = fast_sigmoid(rp.y + br1);
            float zg0 = fast_sigmoid(zp.x + bz0), zg1 = fast_sigmoid(zp.y + bz1);
            float ng0 = fast_tanh(xv.x + bxn0 + rg0*(hv.x + bhn0));
            float ng1 = fast_tanh(xv.y + bxn1 + rg1*(hv.y + bhn1));
            hr0 = (1.f - zg0)*ng0 + zg0*hr0;
            hr1 = (1.f - zg1)*ng1 + zg1*hr1;
            unsigned hp = pack_h2f(hr0, hr1);
            sm[O_ACAT + (64+np)*8 + r] = hp;
            out0g[(rowbase + t)*32 + np] = hp;
        }
        __syncthreads();
    }
    *reinterpret_cast<float2*>(hf0g + (size_t)(b0+r)*64 + 2*np) = make_float2(hr0, hr1);
}

// ---------- kernel 3: GRU layer 1 + prediction head ----------
#define OW1_RZ  0        // [64][128]
#define OW1_XN  8192     // [32][64]
#define OW1_HN  10240    // [32][64]
#define O1_ACAT 12288    // [64][8]  (0..31 out0, 32..63 h1s)
#define O1_GACC 12800    // float [4][8][64]
#define LDS3_U32 14848

__global__ __launch_bounds__(256, 1)
void nbst_gru1(const unsigned* __restrict__ out0g, const float* __restrict__ hf0g,
               const float* __restrict__ Wih1, const float* __restrict__ Whh1,
               const float* __restrict__ bih1, const float* __restrict__ bhh1,
               const float* __restrict__ Wpred, const float* __restrict__ bpred,
               float* __restrict__ outp)
{
    extern __shared__ unsigned sm[];
    float* smF = reinterpret_cast<float*>(sm);
    const int tid = threadIdx.x;
    const int b0 = blockIdx.x * 8;

    for (int e = tid; e < 64*128; e += 256){
        int kk = e >> 7, g = e & 127;
        float w0, w1;
        if (kk < 32){ w0 = Wih1[g*64 + 2*kk];      w1 = Wih1[g*64 + 2*kk + 1]; }
        else { int k2 = kk - 32; w0 = Whh1[g*64 + 2*k2]; w1 = Whh1[g*64 + 2*k2 + 1]; }
        sm[OW1_RZ + e] = pack_h2f(w0, w1);
    }
    for (int e = tid; e < 32*64; e += 256){
        int kk = e >> 6, n = e & 63;
        sm[OW1_XN + e] = pack_h2f(Wih1[(128+n)*64 + 2*kk], Wih1[(128+n)*64 + 2*kk + 1]);
        sm[OW1_HN + e] = pack_h2f(Whh1[(128+n)*64 + 2*kk], Whh1[(128+n)*64 + 2*kk + 1]);
    }
    sm[O1_ACAT + 32*8 + tid] = 0u;   // h1s(0)=0

    const int np = tid & 31, r = tid >> 5;
    const int wv = tid >> 6, l = tid & 63, gs = l & 15, rs = l >> 4;
    const size_t rowbase = (size_t)(b0 + r) * S_;
    const float br0 = bih1[2*np]      + bhh1[2*np];
    const float br1 = bih1[2*np+1]    + bhh1[2*np+1];
    const float bz0 = bih1[64+2*np]   + bhh1[64+2*np];
    const float bz1 = bih1[64+2*np+1] + bhh1[64+2*np+1];
    const float bxn0 = bih1[128+2*np], bxn1 = bih1[128+2*np+1];
    const float bhn0 = bhh1[128+2*np], bhn1 = bhh1[128+2*np+1];
    float hr0 = 0.f, hr1 = 0.f;
    unsigned ureg = out0g[rowbase*32 + np];
    __syncthreads();

    for (int t = 0; t < S_; ++t){
        sm[O1_ACAT + np*8 + r] = ureg;
        { int tn = (t + 1 < S_) ? t + 1 : t; ureg = out0g[(rowbase + tn)*32 + np]; }
        __syncthreads();
        // DOT
        {
            float a00=0,a01=0,a10=0,a11=0,a20=0,a21=0,a30=0,a31=0;
            int wbase, wstr, colo, abase2, nkk;
            if (wv == 0)      { wbase = OW1_RZ; wstr = 128; colo = 0;  abase2 = O1_ACAT;       nkk = 64; }
            else if (wv == 1) { wbase = OW1_RZ; wstr = 128; colo = 64; abase2 = O1_ACAT;       nkk = 64; }
            else if (wv == 2) { wbase = OW1_XN; wstr = 64;  colo = 0;  abase2 = O1_ACAT;       nkk = 32; }
            else              { wbase = OW1_HN; wstr = 64;  colo = 0;  abase2 = O1_ACAT + 256; nkk = 32; }
            const unsigned* wp = sm + wbase + colo + 4*gs;
            const unsigned* ap = sm + abase2 + rs;
            #pragma unroll 4
            for (int kk = 0; kk < nkk; ++kk){
                unsigned aa0 = ap[kk*8], aa1 = ap[kk*8 + 4];
                uint4 wq = *reinterpret_cast<const uint4*>(wp + kk*wstr);
                a00 = dot2h(aa0, wq.x, a00); a01 = dot2h(aa1, wq.x, a01);
                a10 = dot2h(aa0, wq.y, a10); a11 = dot2h(aa1, wq.y, a11);
                a20 = dot2h(aa0, wq.z, a20); a21 = dot2h(aa1, wq.z, a21);
                a30 = dot2h(aa0, wq.w, a30); a31 = dot2h(aa1, wq.w, a31);
            }
            *reinterpret_cast<float4*>(smF + O1_GACC + (wv*8 + rs)*64 + 4*gs)     = make_float4(a00, a10, a20, a30);
            *reinterpret_cast<float4*>(smF + O1_GACC + (wv*8 + rs + 4)*64 + 4*gs) = make_float4(a01, a11, a21, a31);
        }
        __syncthreads();
        // GATE
        {
            const float* gF = smF + O1_GACC;
            float2 rp = *reinterpret_cast<const float2*>(gF + (0*8 + r)*64 + 2*np);
            float2 zp = *reinterpret_cast<const float2*>(gF + (1*8 + r)*64 + 2*np);
            float2 xv = *reinterpret_cast<const float2*>(gF + (2*8 + r)*64 + 2*np);
            float2 hv = *reinterpret_cast<const float2*>(gF + (3*8 + r)*64 + 2*np);
            float rg0 = fast_sigmoid(rp.x + br0), rg1 = fast_sigmoid(rp.y + br1);
            float zg0 = fast_sigmoid(zp.x + bz0), zg1 = fast_sigmoid(zp.y + bz1);
            float ng0 = fast_tanh(xv.x + bxn0 + rg0*(hv.x + bhn0));
            float ng1 = fast_tanh(xv.y + bxn1 + rg1*(hv.y + bhn1));
            hr0 = (1.f - zg0)*ng0 + zg0*hr0;
            hr1 = (1.f - zg1)*ng1 + zg1*hr1;
            sm[O1_ACAT + (32+np)*8 + r] = pack_h2f(hr0, hr1);
        }
        __syncthreads();
    }
    // pred: tanh([hf0, hf1] @ W_pred^T + b_pred)
    float2 f0 = *reinterpret_cast<const float2*>(hf0g + (size_t)(b0+r)*64 + 2*np);
    float part = f0.x * Wpred[2*np] + f0.y * Wpred[2*np+1]
               + hr0 * Wpred[64+2*np] + hr1 * Wpred[64+2*np+1];
    #pragma unroll
    for (int s2 = 16; s2 >= 1; s2 >>= 1) part += __shfl_xor(part, s2);
    if (np == 0) outp[b0 + r] = fast_tanh(part + bpred[0]);
}

// ---------- launcher ----------
extern "C" void kernel_launch(void* const* d_in, const int* in_sizes, int n_in,
                              void* d_out, int out_size, void* d_ws, size_t ws_size,
                              hipStream_t stream) {
    (void)in_sizes; (void)n_in; (void)out_size; (void)ws_size;
    const float* station_nodes    = (const float*)d_in[1];
    const float* station_features = (const float*)d_in[2];
    const int*   station_emb      = (const int*)d_in[3];
    const float* e0 = (const float*)d_in[4];
    const float* e1 = (const float*)d_in[5];
    const float* e2 = (const float*)d_in[6];
    const float* e3 = (const float*)d_in[7];
    const float* e4 = (const float*)d_in[8];
    const float* W_nodes = (const float*)d_in[9];
    const float* b_nodes = (const float*)d_in[10];
    const float* W_attn  = (const float*)d_in[11];
    const float* W_d1 = (const float*)d_in[13];
    const float* b_d1 = (const float*)d_in[14];
    const float* W_d2 = (const float*)d_in[15];
    const float* b_d2 = (const float*)d_in[16];
    const float* Wih0 = (const float*)d_in[17];
    const float* Whh0 = (const float*)d_in[18];
    const float* bih0 = (const float*)d_in[19];
    const float* bhh0 = (const float*)d_in[20];
    const float* Wih1 = (const float*)d_in[21];
    const float* Whh1 = (const float*)d_in[22];
    const float* bih1 = (const float*)d_in[23];
    const float* bhh1 = (const float*)d_in[24];
    const float* W_pred = (const float*)d_in[25];
    const float* b_pred = (const float*)d_in[26];
    float* outp = (float*)d_out;

    char* ws = (char*)d_ws;
    float*    attnW  = (float*)ws;                       // B*64 f32   = 512 KB
    float*    hf0    = (float*)(ws + 524288);            // B*64 f32   = 512 KB
    unsigned* out0pk = (unsigned*)(ws + 1048576);        // B*S*32 u32 = 44 MB

    hipFuncSetAttribute((const void*)nbst_gru0, hipFuncAttributeMaxDynamicSharedMemorySize, 160*1024);
    hipFuncSetAttribute((const void*)nbst_gru1, hipFuncAttributeMaxDynamicSharedMemorySize, 64*1024);

    nbst_attn<<<dim3(512), dim3(256), 0, stream>>>(station_nodes, W_nodes, b_nodes, W_attn, attnW);
    nbst_gru0<<<dim3(256), dim3(256), LDS2_U32*4, stream>>>(
        station_features, station_emb, e0, e1, e2, e3, e4,
        W_d1, b_d1, W_d2, b_d2, Wih0, Whh0, bih0, bhh0, attnW, out0pk, hf0);
    nbst_gru1<<<dim3(256), dim3(256), LDS3_U32*4, stream>>>(
        out0pk, hf0, Wih1, Whh1, bih1, bhh1, W_pred, b_pred, outp);
}

// Round 2
// 651.061 us; speedup vs baseline: 1.7007x; 1.7007x over previous
//
#include <hip/hip_runtime.h>
#include <cstdint>
#include <cstddef>

#define B_ 2048
#define S_ 168

// ---------- helpers ----------
typedef _Float16 h2_t __attribute__((ext_vector_type(2)));

__device__ __forceinline__ float dot2h(unsigned a, unsigned b, float c){
    return __builtin_amdgcn_fdot2(__builtin_bit_cast(h2_t, a),
                                  __builtin_bit_cast(h2_t, b), c, false);
}
__device__ __forceinline__ unsigned pack_h2f(float a, float b){
    h2_t v; v.x = (_Float16)a; v.y = (_Float16)b;
    return __builtin_bit_cast(unsigned, v);
}
__device__ __forceinline__ float fast_exp(float x){      // e^x
    return __builtin_amdgcn_exp2f(x * 1.44269504088896340736f);
}
__device__ __forceinline__ float fast_sigmoid(float x){
    return __builtin_amdgcn_rcpf(1.0f + fast_exp(-x));
}
__device__ __forceinline__ float fast_tanh(float x){
    return 1.0f - 2.0f * __builtin_amdgcn_rcpf(1.0f + fast_exp(2.0f * x));
}
// within-wave LDS producer->consumer fence (no __syncthreads needed)
__device__ __forceinline__ void wsync(){
    asm volatile("s_waitcnt lgkmcnt(0)" ::: "memory");
    __builtin_amdgcn_wave_barrier();
}

// ---------- kernel 1: attention over stations (unchanged, proven) ----------
__global__ void nbst_attn(const float* __restrict__ sn, const float* __restrict__ Wn,
                          const float* __restrict__ bn, const float* __restrict__ Wa,
                          float* __restrict__ attnO){
    __shared__ float WnL[64*16];
    __shared__ float WsL[64];
    __shared__ float bnL[64];
    const int tid = threadIdx.x;
    for (int e = tid; e < 1024; e += 256) WnL[e] = Wn[e];
    if (tid < 64){ WsL[tid] = Wa[64 + tid]; bnL[tid] = bn[tid]; }
    __syncthreads();
    const int wv = tid >> 6, l = tid & 63;
    const int b = blockIdx.x * 4 + wv;
    const float* xp = sn + ((size_t)b * 64 + l) * 16;
    float x[16];
    #pragma unroll
    for (int k = 0; k < 16; ++k) x[k] = xp[k];
    float e_i = 0.f;
    for (int h = 0; h < 64; ++h){
        float acc = bnL[h];
        #pragma unroll
        for (int k = 0; k < 16; ++k) acc += x[k] * WnL[h*16 + k];
        e_i += fast_tanh(acc) * WsL[h];
    }
    float m = e_i;
    #pragma unroll
    for (int s = 32; s >= 1; s >>= 1) m = fmaxf(m, __shfl_xor(m, s));
    float p = fast_exp(e_i - m);
    float ssum = p;
    #pragma unroll
    for (int s = 32; s >= 1; s >>= 1) ssum += __shfl_xor(ssum, s);
    attnO[(size_t)b*64 + l] = p * __builtin_amdgcn_rcpf(ssum);
}

// ---------- kernel 2: fused mlp + GRU layer 0, wave-per-row ----------
// LDS map (u32 units)
#define R0_WIH  0            // [192 g][68] fp16-pairs, kk 0..63 used (stride 68 -> conflict-free b128)
#define R0_WD1  13056        // [32 o][20], kk 0..17 used, pads ZERO
#define R0_WD2  13696        // [64 o][20], kk 0..15 used, pads ZERO
#define R0_EMB  14976        // 260 f32
#define R0_WAVE 15240        // per-wave, stride 144
#define R0_CAT  0            // [20] (18 + 2 zero pads)
#define R0_H1P  20           // [16]
#define R0_FEAT 36           // [64]  (fA pairs 0..31 | sfe pairs 32..63)
#define R0_HP   100          // [32]
#define R0_TOT  (15240 + 4*144)

__global__ __launch_bounds__(256, 2)
void nbst_rec0(const float* __restrict__ sf, const int* __restrict__ se,
               const float* __restrict__ e0, const float* __restrict__ e1,
               const float* __restrict__ e2, const float* __restrict__ e3,
               const float* __restrict__ e4,
               const float* __restrict__ Wd1, const float* __restrict__ bd1,
               const float* __restrict__ Wd2, const float* __restrict__ bd2,
               const float* __restrict__ Wih0, const float* __restrict__ Whh0,
               const float* __restrict__ bih0, const float* __restrict__ bhh0,
               const float* __restrict__ attnI,
               unsigned* __restrict__ out0g, float* __restrict__ hf0g)
{
    __shared__ unsigned sm[R0_TOT];
    float* smF = reinterpret_cast<float*>(sm);
    const int tid = threadIdx.x;

    // ---- stage shared weights (block-cooperative, once) ----
    for (int e = tid; e < 192*64; e += 256){
        int g = e >> 6, kk = e & 63;
        sm[R0_WIH + g*68 + kk] = pack_h2f(Wih0[g*128 + 2*kk], Wih0[g*128 + 2*kk + 1]);
    }
    for (int e = tid; e < 640; e += 256){
        int o = e / 20, kk = e % 20;
        sm[R0_WD1 + e] = (kk < 18) ? pack_h2f(Wd1[o*36 + 2*kk], Wd1[o*36 + 2*kk + 1]) : 0u;
    }
    for (int e = tid; e < 1280; e += 256){
        int o = e / 20, kk = e % 20;
        sm[R0_WD2 + e] = (kk < 16) ? pack_h2f(Wd2[o*32 + 2*kk], Wd2[o*32 + 2*kk + 1]) : 0u;
    }
    for (int e = tid; e < 260; e += 256){
        float v;
        if (e < 48)       v = e0[e];
        else if (e < 88)  v = e1[e-48];
        else if (e < 136) v = e2[e-88];
        else if (e < 164) v = e3[e-136];
        else              v = e4[e-164];
        smF[R0_EMB + e] = v;
    }

    const int wv = tid >> 6, l = tid & 63;
    const int b = blockIdx.x * 4 + wv;
    const int wb = R0_WAVE + wv * 144;
    if (l >= 18 && l < 20) sm[wb + R0_CAT + l] = 0u;  // zero cat pads (read by padded H1 dot)
    if (l < 32) sm[wb + R0_HP + l] = 0u;              // h(0) = 0

    // ---- Whh0 rows l / 64+l / 128+l -> 96 persistent VGPRs (static-indexed only) ----
    unsigned whr[32], whz[32], whn[32];
    {
        const float4* p0 = reinterpret_cast<const float4*>(Whh0) + (size_t)l*16;
        const float4* p1 = reinterpret_cast<const float4*>(Whh0) + (size_t)(64+l)*16;
        const float4* p2 = reinterpret_cast<const float4*>(Whh0) + (size_t)(128+l)*16;
        #pragma unroll
        for (int i = 0; i < 16; ++i){
            float4 a = p0[i]; whr[2*i] = pack_h2f(a.x, a.y); whr[2*i+1] = pack_h2f(a.z, a.w);
            float4 c = p1[i]; whz[2*i] = pack_h2f(c.x, c.y); whz[2*i+1] = pack_h2f(c.z, c.w);
            float4 d = p2[i]; whn[2*i] = pack_h2f(d.x, d.y); whn[2*i+1] = pack_h2f(d.z, d.w);
        }
    }

    const float aAl  = attnI[(size_t)b*64 + l];
    const float bd1r = bd1[l & 31];
    const float bd2r = bd2[l];
    const float br   = bih0[l]      + bhh0[l];
    const float bz   = bih0[64+l]   + bhh0[64+l];
    const float bxn  = bih0[128+l];
    const float bhn  = bhh0[128+l];
    float hreg = 0.f;

    const size_t rb = (size_t)b * S_;
    float v0r = 0.f, v1r = 0.f; int idxr = 0;
    if (l < 8){ v0r = sf[rb*16 + 2*l]; v1r = sf[rb*16 + 2*l + 1]; }
    else if (l < 18){ idxr = se[rb*5 + ((l-8)>>1)]; }

    __syncthreads();

    #pragma unroll 1
    for (int t = 0; t < S_; ++t){
        // ---- CAT (lanes 0..17 produce packed pairs) ----
        if (l < 18){
            float c0, c1;
            if (l < 8){ c0 = v0r; c1 = v1r; }
            else {
                const int j = 2*l - 16, ebl = j >> 2, d0 = j & 3;
                const int toff = (ebl==0)?0:(ebl==1)?48:(ebl==2)?88:(ebl==3)?136:164;
                const int idx = idxr - (ebl >= 2 ? 1 : 0);
                c0 = smF[R0_EMB + toff + idx*4 + d0];
                c1 = smF[R0_EMB + toff + idx*4 + d0 + 1];
            }
            sm[wb + R0_CAT + l] = pack_h2f(c0, c1);
        }
        {   // prefetch t+1 globals
            const int tn = (t + 1 < S_) ? t + 1 : t;
            if (l < 8){ v0r = sf[(rb+tn)*16 + 2*l]; v1r = sf[(rb+tn)*16 + 2*l + 1]; }
            else if (l < 18){ idxr = se[(rb+tn)*5 + ((l-8)>>1)]; }
        }
        wsync();
        // ---- H1: lane computes h1[l&31] (upper half redundant) ----
        {
            float acc = bd1r;
            const unsigned* wp = sm + R0_WD1 + (l & 31)*20;
            const unsigned* cp = sm + wb + R0_CAT;
            #pragma unroll
            for (int k = 0; k < 5; ++k){
                uint4 w = *reinterpret_cast<const uint4*>(wp + 4*k);
                uint4 a = *reinterpret_cast<const uint4*>(cp + 4*k);
                acc = dot2h(a.x, w.x, acc); acc = dot2h(a.y, w.y, acc);
                acc = dot2h(a.z, w.z, acc); acc = dot2h(a.w, w.w, acc);
            }
            float th = fast_tanh(acc);
            float tp = __shfl_xor(th, 1);
            if (!(l & 1) && l < 32) sm[wb + R0_H1P + (l>>1)] = pack_h2f(th, tp);
        }
        wsync();
        // ---- SFE: lane computes sfe[l]; writes fA & sfe packed panels ----
        {
            float acc = bd2r;
            const unsigned* wp = sm + R0_WD2 + l*20;
            const unsigned* ap = sm + wb + R0_H1P;
            #pragma unroll
            for (int k = 0; k < 4; ++k){
                uint4 w = *reinterpret_cast<const uint4*>(wp + 4*k);
                uint4 a = *reinterpret_cast<const uint4*>(ap + 4*k);
                acc = dot2h(a.x, w.x, acc); acc = dot2h(a.y, w.y, acc);
                acc = dot2h(a.z, w.z, acc); acc = dot2h(a.w, w.w, acc);
            }
            float s  = fast_tanh(acc);
            float fa = aAl * s;
            float sp  = __shfl_xor(s, 1);
            float fap = __shfl_xor(fa, 1);
            if (!(l & 1)){
                sm[wb + R0_FEAT + (l>>1)]      = pack_h2f(fa, fap);
                sm[wb + R0_FEAT + 32 + (l>>1)] = pack_h2f(s, sp);
            }
        }
        wsync();
        // ---- fused xg (LDS weights) + hh (reg weights) dot ----
        float ar = 0.f, az = 0.f, axn = 0.f, ahn = 0.f;
        {
            const unsigned* w0 = sm + R0_WIH + l*68;
            const unsigned* w1 = sm + R0_WIH + (64+l)*68;
            const unsigned* w2 = sm + R0_WIH + (128+l)*68;
            const unsigned* fp = sm + wb + R0_FEAT;
            #pragma unroll
            for (int k = 0; k < 16; ++k){
                uint4 f   = *reinterpret_cast<const uint4*>(fp + 4*k);
                uint4 wa  = *reinterpret_cast<const uint4*>(w0 + 4*k);
                uint4 wbq = *reinterpret_cast<const uint4*>(w1 + 4*k);
                uint4 wc  = *reinterpret_cast<const uint4*>(w2 + 4*k);
                ar  = dot2h(f.x, wa.x,  ar);  ar  = dot2h(f.y, wa.y,  ar);
                ar  = dot2h(f.z, wa.z,  ar);  ar  = dot2h(f.w, wa.w,  ar);
                az  = dot2h(f.x, wbq.x, az);  az  = dot2h(f.y, wbq.y, az);
                az  = dot2h(f.z, wbq.z, az);  az  = dot2h(f.w, wbq.w, az);
                axn = dot2h(f.x, wc.x, axn);  axn = dot2h(f.y, wc.y, axn);
                axn = dot2h(f.z, wc.z, axn);  axn = dot2h(f.w, wc.w, axn);
            }
            const unsigned* hp = sm + wb + R0_HP;
            #pragma unroll
            for (int k = 0; k < 8; ++k){
                uint4 hv = *reinterpret_cast<const uint4*>(hp + 4*k);
                ar  = dot2h(hv.x, whr[4*k],   ar);  ar  = dot2h(hv.y, whr[4*k+1], ar);
                ar  = dot2h(hv.z, whr[4*k+2], ar);  ar  = dot2h(hv.w, whr[4*k+3], ar);
                az  = dot2h(hv.x, whz[4*k],   az);  az  = dot2h(hv.y, whz[4*k+1], az);
                az  = dot2h(hv.z, whz[4*k+2], az);  az  = dot2h(hv.w, whz[4*k+3], az);
                ahn = dot2h(hv.x, whn[4*k],   ahn); ahn = dot2h(hv.y, whn[4*k+1], ahn);
                ahn = dot2h(hv.z, whn[4*k+2], ahn); ahn = dot2h(hv.w, whn[4*k+3], ahn);
            }
        }
        // ---- gates + state update ----
        {
            float rg = fast_sigmoid(ar + br);
            float zg = fast_sigmoid(az + bz);
            float ng = fast_tanh(axn + bxn + rg*(ahn + bhn));
            hreg = (1.f - zg)*ng + zg*hreg;
            float hp2 = __shfl_xor(hreg, 1);
            if (!(l & 1)){
                unsigned hu = pack_h2f(hreg, hp2);
                sm[wb + R0_HP + (l>>1)] = hu;     // drained by next step's first wsync
                out0g[(rb + t)*32 + (l>>1)] = hu;
            }
        }
    }
    hf0g[(size_t)b*64 + l] = hreg;
}

// ---------- kernel 3: fused xg1 + GRU layer 1 + pred, wave-per-row ----------
#define R1_WIH  0        // [192 g][36], kk 0..31 used (stride 36 -> conflict-free b128)
#define R1_WAVE 6912     // per-wave stride 64: xa[32] @0, hp[32] @32
#define R1_TOT  (6912 + 4*64)

__global__ __launch_bounds__(256, 2)
void nbst_rec1(const unsigned* __restrict__ out0g, const float* __restrict__ hf0g,
               const float* __restrict__ Wih1, const float* __restrict__ Whh1,
               const float* __restrict__ bih1, const float* __restrict__ bhh1,
               const float* __restrict__ Wpred, const float* __restrict__ bpred,
               float* __restrict__ outp)
{
    __shared__ unsigned sm[R1_TOT];
    const int tid = threadIdx.x;
    for (int e = tid; e < 192*32; e += 256){
        int g = e >> 5, kk = e & 31;
        sm[R1_WIH + g*36 + kk] = pack_h2f(Wih1[g*64 + 2*kk], Wih1[g*64 + 2*kk + 1]);
    }
    const int wv = tid >> 6, l = tid & 63;
    const int b = blockIdx.x * 4 + wv;
    const int wb = R1_WAVE + wv * 64;
    if (l < 32) sm[wb + 32 + l] = 0u;   // h(0)=0

    unsigned whr[32], whz[32], whn[32];
    {
        const float4* p0 = reinterpret_cast<const float4*>(Whh1) + (size_t)l*16;
        const float4* p1 = reinterpret_cast<const float4*>(Whh1) + (size_t)(64+l)*16;
        const float4* p2 = reinterpret_cast<const float4*>(Whh1) + (size_t)(128+l)*16;
        #pragma unroll
        for (int i = 0; i < 16; ++i){
            float4 a = p0[i]; whr[2*i] = pack_h2f(a.x, a.y); whr[2*i+1] = pack_h2f(a.z, a.w);
            float4 c = p1[i]; whz[2*i] = pack_h2f(c.x, c.y); whz[2*i+1] = pack_h2f(c.z, c.w);
            float4 d = p2[i]; whn[2*i] = pack_h2f(d.x, d.y); whn[2*i+1] = pack_h2f(d.z, d.w);
        }
    }
    const float br  = bih1[l]      + bhh1[l];
    const float bz  = bih1[64+l]   + bhh1[64+l];
    const float bxn = bih1[128+l];
    const float bhn = bhh1[128+l];
    float hreg = 0.f;
    const size_t rb = (size_t)b * S_;
    unsigned xreg = (l < 32) ? out0g[rb*32 + l] : 0u;

    __syncthreads();

    #pragma unroll 1
    for (int t = 0; t < S_; ++t){
        if (l < 32) sm[wb + l] = xreg;
        {   const int tn = (t + 1 < S_) ? t + 1 : t;
            if (l < 32) xreg = out0g[(rb + tn)*32 + l]; }
        wsync();
        float ar = 0.f, az = 0.f, axn = 0.f, ahn = 0.f;
        {
            const unsigned* w0 = sm + R1_WIH + l*36;
            const unsigned* w1 = sm + R1_WIH + (64+l)*36;
            const unsigned* w2 = sm + R1_WIH + (128+l)*36;
            const unsigned* xp = sm + wb;
            #pragma unroll
            for (int k = 0; k < 8; ++k){
                uint4 x   = *reinterpret_cast<const uint4*>(xp + 4*k);
                uint4 wa  = *reinterpret_cast<const uint4*>(w0 + 4*k);
                uint4 wbq = *reinterpret_cast<const uint4*>(w1 + 4*k);
                uint4 wc  = *reinterpret_cast<const uint4*>(w2 + 4*k);
                ar  = dot2h(x.x, wa.x,  ar);  ar  = dot2h(x.y, wa.y,  ar);
                ar  = dot2h(x.z, wa.z,  ar);  ar  = dot2h(x.w, wa.w,  ar);
                az  = dot2h(x.x, wbq.x, az);  az  = dot2h(x.y, wbq.y, az);
                az  = dot2h(x.z, wbq.z, az);  az  = dot2h(x.w, wbq.w, az);
                axn = dot2h(x.x, wc.x, axn);  axn = dot2h(x.y, wc.y, axn);
                axn = dot2h(x.z, wc.z, axn);  axn = dot2h(x.w, wc.w, axn);
            }
            const unsigned* hp = sm + wb + 32;
            #pragma unroll
            for (int k = 0; k < 8; ++k){
                uint4 hv = *reinterpret_cast<const uint4*>(hp + 4*k);
                ar  = dot2h(hv.x, whr[4*k],   ar);  ar  = dot2h(hv.y, whr[4*k+1], ar);
                ar  = dot2h(hv.z, whr[4*k+2], ar);  ar  = dot2h(hv.w, whr[4*k+3], ar);
                az  = dot2h(hv.x, whz[4*k],   az);  az  = dot2h(hv.y, whz[4*k+1], az);
                az  = dot2h(hv.z, whz[4*k+2], az);  az  = dot2h(hv.w, whz[4*k+3], az);
                ahn = dot2h(hv.x, whn[4*k],   ahn); ahn = dot2h(hv.y, whn[4*k+1], ahn);
                ahn = dot2h(hv.z, whn[4*k+2], ahn); ahn = dot2h(hv.w, whn[4*k+3], ahn);
            }
        }
        {
            float rg = fast_sigmoid(ar + br);
            float zg = fast_sigmoid(az + bz);
            float ng = fast_tanh(axn + bxn + rg*(ahn + bhn));
            hreg = (1.f - zg)*ng + zg*hreg;
            float hp2 = __shfl_xor(hreg, 1);
            if (!(l & 1)) sm[wb + 32 + (l>>1)] = pack_h2f(hreg, hp2);
        }
    }
    // pred: tanh([hf0, hf1] @ W_pred^T + b_pred)
    float hf0v = hf0g[(size_t)b*64 + l];
    float part = hf0v * Wpred[l] + hreg * Wpred[64 + l];
    #pragma unroll
    for (int s = 32; s >= 1; s >>= 1) part += __shfl_xor(part, s);
    if (l == 0) outp[b] = fast_tanh(part + bpred[0]);
}

// ---------- launcher ----------
extern "C" void kernel_launch(void* const* d_in, const int* in_sizes, int n_in,
                              void* d_out, int out_size, void* d_ws, size_t ws_size,
                              hipStream_t stream) {
    (void)in_sizes; (void)n_in; (void)out_size; (void)ws_size;
    const float* station_nodes    = (const float*)d_in[1];
    const float* station_features = (const float*)d_in[2];
    const int*   station_emb      = (const int*)d_in[3];
    const float* e0 = (const float*)d_in[4];
    const float* e1 = (const float*)d_in[5];
    const float* e2 = (const float*)d_in[6];
    const float* e3 = (const float*)d_in[7];
    const float* e4 = (const float*)d_in[8];
    const float* W_nodes = (const float*)d_in[9];
    const float* b_nodes = (const float*)d_in[10];
    const float* W_attn  = (const float*)d_in[11];
    const float* W_d1 = (const float*)d_in[13];
    const float* b_d1 = (const float*)d_in[14];
    const float* W_d2 = (const float*)d_in[15];
    const float* b_d2 = (const float*)d_in[16];
    const float* Wih0 = (const float*)d_in[17];
    const float* Whh0 = (const float*)d_in[18];
    const float* bih0 = (const float*)d_in[19];
    const float* bhh0 = (const float*)d_in[20];
    const float* Wih1 = (const float*)d_in[21];
    const float* Whh1 = (const float*)d_in[22];
    const float* bih1 = (const float*)d_in[23];
    const float* bhh1 = (const float*)d_in[24];
    const float* W_pred = (const float*)d_in[25];
    const float* b_pred = (const float*)d_in[26];
    float* outp = (float*)d_out;

    char* ws = (char*)d_ws;
    float*    attnW  = (float*)ws;                 // B*64 f32   = 512 KB
    float*    hf0    = (float*)(ws + 524288);      // B*64 f32   = 512 KB
    unsigned* out0pk = (unsigned*)(ws + 1048576);  // B*S*32 u32 = 44 MB

    nbst_attn<<<dim3(512), dim3(256), 0, stream>>>(station_nodes, W_nodes, b_nodes, W_attn, attnW);
    nbst_rec0<<<dim3(512), dim3(256), 0, stream>>>(
        station_features, station_emb, e0, e1, e2, e3, e4,
        W_d1, b_d1, W_d2, b_d2, Wih0, Whh0, bih0, bhh0, attnW, out0pk, hf0);
    nbst_rec1<<<dim3(512), dim3(256), 0, stream>>>(
        out0pk, hf0, Wih1, Whh1, bih1, bhh1, W_pred, b_pred, outp);
}

// Round 3
// 487.653 us; speedup vs baseline: 2.2706x; 1.3351x over previous
//
#include <hip/hip_runtime.h>
#include <cstdint>
#include <cstddef>

#define B_ 2048
#define S_ 168

// ---------- helpers ----------
typedef _Float16 h2_t __attribute__((ext_vector_type(2)));
typedef _Float16 f16x8 __attribute__((ext_vector_type(8)));
typedef float f32x4 __attribute__((ext_vector_type(4)));
typedef unsigned int u32;

__device__ __forceinline__ float dot2h(unsigned a, unsigned b, float c){
    return __builtin_amdgcn_fdot2(__builtin_bit_cast(h2_t, a),
                                  __builtin_bit_cast(h2_t, b), c, false);
}
__device__ __forceinline__ unsigned pack_h2f(float a, float b){
    h2_t v; v.x = (_Float16)a; v.y = (_Float16)b;
    return __builtin_bit_cast(unsigned, v);
}
__device__ __forceinline__ float fast_exp(float x){
    return __builtin_amdgcn_exp2f(x * 1.44269504088896340736f);
}
__device__ __forceinline__ float fast_sigmoid(float x){
    return __builtin_amdgcn_rcpf(1.0f + fast_exp(-x));
}
__device__ __forceinline__ float fast_tanh(float x){
    return 1.0f - 2.0f * __builtin_amdgcn_rcpf(1.0f + fast_exp(2.0f * x));
}
__device__ __forceinline__ void wsync(){
    asm volatile("s_waitcnt lgkmcnt(0)" ::: "memory");
    __builtin_amdgcn_wave_barrier();
}
__device__ __forceinline__ f32x4 mfma16(uint4 a, uint4 b, f32x4 c){
    return __builtin_amdgcn_mfma_f32_16x16x32_f16(
        __builtin_bit_cast(f16x8, a), __builtin_bit_cast(f16x8, b), c, 0, 0, 0);
}
// B-fragment for mfma_f32_16x16x32_f16 from row-major f32 W[rows][ldk]:
// lane provides W[o][kk0+e] as halfs e=0..7; zero-padded beyond kmax.
__device__ __forceinline__ uint4 load_bfrag(const float* __restrict__ W, int ldk,
                                            int o, int kk0, int kmax){
    float w[8];
    #pragma unroll
    for (int e = 0; e < 8; ++e){
        int kk = kk0 + e;
        w[e] = (kk < kmax) ? W[o*ldk + kk] : 0.f;
    }
    uint4 r;
    r.x = pack_h2f(w[0], w[1]); r.y = pack_h2f(w[2], w[3]);
    r.z = pack_h2f(w[4], w[5]); r.w = pack_h2f(w[6], w[7]);
    return r;
}

// ---------- kernel 1: attention over stations (proven) ----------
__global__ void nbst_attn(const float* __restrict__ sn, const float* __restrict__ Wn,
                          const float* __restrict__ bn, const float* __restrict__ Wa,
                          float* __restrict__ attnO){
    __shared__ float WnL[64*16];
    __shared__ float WsL[64];
    __shared__ float bnL[64];
    const int tid = threadIdx.x;
    for (int e = tid; e < 1024; e += 256) WnL[e] = Wn[e];
    if (tid < 64){ WsL[tid] = Wa[64 + tid]; bnL[tid] = bn[tid]; }
    __syncthreads();
    const int wv = tid >> 6, l = tid & 63;
    const int b = blockIdx.x * 4 + wv;
    const float* xp = sn + ((size_t)b * 64 + l) * 16;
    float x[16];
    #pragma unroll
    for (int k = 0; k < 16; ++k) x[k] = xp[k];
    float e_i = 0.f;
    for (int h = 0; h < 64; ++h){
        float acc = bnL[h];
        #pragma unroll
        for (int k = 0; k < 16; ++k) acc += x[k] * WnL[h*16 + k];
        e_i += fast_tanh(acc) * WsL[h];
    }
    float m = e_i;
    #pragma unroll
    for (int s = 32; s >= 1; s >>= 1) m = fmaxf(m, __shfl_xor(m, s));
    float p = fast_exp(e_i - m);
    float ssum = p;
    #pragma unroll
    for (int s = 32; s >= 1; s >>= 1) ssum += __shfl_xor(ssum, s);
    attnO[(size_t)b*64 + l] = p * __builtin_amdgcn_rcpf(ssum);
}

// ---------- kernel 2: time-parallel MLP + xg0 GEMM (MFMA) ----------
// 64-row tiles over B*S=344064 rows. xg0[row][192] f16 = feat[row][128] @ Wih0^T.
#define A0_CAT 0      // [64][36] u32: 0..17 cat pairs, 18..31 zero (K padded 36->64)
#define A0_H1  2304   // [64][20] u32: 0..15 h1 pairs
#define A0_FT  3584   // [64][68] u32: 0..31 fa pairs, 32..63 sfe pairs
#define A0_WM  7936   // [8 frags][64 lanes][4] : 0..3 Wd1(n,ks), 4..7 Wd2(n)
#define A0_EMB 9984   // 260 f32
#define A0_TOT 10244

__global__ __launch_bounds__(256, 2)
void nbst_mlpxg0(const float* __restrict__ sf, const int* __restrict__ se,
                 const float* __restrict__ e0, const float* __restrict__ e1,
                 const float* __restrict__ e2, const float* __restrict__ e3,
                 const float* __restrict__ e4,
                 const float* __restrict__ Wd1, const float* __restrict__ bd1,
                 const float* __restrict__ Wd2, const float* __restrict__ bd2,
                 const float* __restrict__ Wih0, const float* __restrict__ attnI,
                 unsigned* __restrict__ xgout)
{
    __shared__ u32 sm[A0_TOT];
    float* smF = reinterpret_cast<float*>(sm);
    const int tid = threadIdx.x;
    const int w = tid >> 6, l = tid & 63;
    const int R0 = blockIdx.x * 64;

    // stage emb tables
    for (int e = tid; e < 260; e += 256){
        float v;
        if (e < 48)       v = e0[e];
        else if (e < 88)  v = e1[e-48];
        else if (e < 136) v = e2[e-88];
        else if (e < 164) v = e3[e-136];
        else              v = e4[e-164];
        smF[A0_EMB + e] = v;
    }
    __syncthreads();

    // stage MLP B-frags into LDS (shared by all waves)
    for (int f = w; f < 8; f += 4){
        uint4 fr;
        if (f < 4){ int n = f >> 1, ks = f & 1;
                    fr = load_bfrag(Wd1, 36, 16*n + (l&15), 32*ks + 8*(l>>4), 36); }
        else      { int n = f - 4;
                    fr = load_bfrag(Wd2, 32, 16*n + (l&15), 8*(l>>4), 32); }
        *reinterpret_cast<uint4*>(sm + A0_WM + (f*64 + l)*4) = fr;
    }
    // Wih0 B-frags in registers: wave covers cols {w, w+4, w+8} x 16
    uint4 bw[3][4];
    #pragma unroll
    for (int nn = 0; nn < 3; ++nn)
        #pragma unroll
        for (int ks = 0; ks < 4; ++ks)
            bw[nn][ks] = load_bfrag(Wih0, 128, 16*(w + 4*nn) + (l&15), 32*ks + 8*(l>>4), 128);
    // attn preload for sfe phase: rows 16w+4*(l>>4)+j, cols 16n+(l&15)
    float attv[4][4];
    #pragma unroll
    for (int j = 0; j < 4; ++j){
        int row = 16*w + 4*(l>>4) + j;
        int b = (R0 + row) / S_;
        #pragma unroll
        for (int n = 0; n < 4; ++n)
            attv[j][n] = attnI[(size_t)b*64 + 16*n + (l&15)];
    }
    // zero CAT K-pad (u32 18..31)
    for (int e = tid; e < 64*14; e += 256){
        int row = e / 14, j = 18 + e % 14;
        sm[A0_CAT + row*36 + j] = 0u;
    }
    // build cat pairs
    for (int e = tid; e < 64*18; e += 256){
        int row = e / 18, j = e % 18;
        int R = R0 + row;
        float c0, c1;
        if (j < 8){
            c0 = sf[(size_t)R*16 + 2*j]; c1 = sf[(size_t)R*16 + 2*j + 1];
        } else {
            int jj = j - 8, ebl = jj >> 1, d0 = (jj & 1) * 2;
            int idx = se[(size_t)R*5 + ebl] - (ebl >= 2 ? 1 : 0);
            const int toff = (ebl==0)?0:(ebl==1)?48:(ebl==2)?88:(ebl==3)?136:164;
            c0 = smF[A0_EMB + toff + idx*4 + d0];
            c1 = smF[A0_EMB + toff + idx*4 + d0 + 1];
        }
        sm[A0_CAT + row*36 + j] = pack_h2f(c0, c1);
    }
    __syncthreads();

    // P1: h1 = tanh(cat @ Wd1^T + bd1)   (wave w owns m-tile w)
    {
        f32x4 c1a[2];
        #pragma unroll
        for (int n = 0; n < 2; ++n){
            float bb = bd1[16*n + (l&15)];
            c1a[n] = (f32x4){bb, bb, bb, bb};
        }
        #pragma unroll
        for (int ks = 0; ks < 2; ++ks){
            uint4 a = *reinterpret_cast<const uint4*>(
                sm + A0_CAT + (16*w + (l&15))*36 + ks*16 + 4*(l>>4));
            #pragma unroll
            for (int n = 0; n < 2; ++n)
                c1a[n] = mfma16(a, *reinterpret_cast<const uint4*>(
                    sm + A0_WM + ((n*2 + ks)*64 + l)*4), c1a[n]);
        }
        #pragma unroll
        for (int n = 0; n < 2; ++n)
            #pragma unroll
            for (int j = 0; j < 4; ++j){
                float v = fast_tanh(c1a[n][j]);
                float vp = __shfl_xor(v, 1);
                if (!(l & 1))
                    sm[A0_H1 + (16*w + 4*(l>>4) + j)*20 + 8*n + ((l&15) >> 1)] = pack_h2f(v, vp);
            }
    }
    wsync();   // H1 row-block w written+read by wave w only

    // P2: sfe = tanh(h1 @ Wd2^T + bd2); feat = [attn*sfe | sfe]
    {
        uint4 a = *reinterpret_cast<const uint4*>(
            sm + A0_H1 + (16*w + (l&15))*20 + 4*(l>>4));
        f32x4 c2[4];
        #pragma unroll
        for (int n = 0; n < 4; ++n){
            float bb = bd2[16*n + (l&15)];
            c2[n] = (f32x4){bb, bb, bb, bb};
            c2[n] = mfma16(a, *reinterpret_cast<const uint4*>(
                sm + A0_WM + ((4 + n)*64 + l)*4), c2[n]);
        }
        #pragma unroll
        for (int n = 0; n < 4; ++n)
            #pragma unroll
            for (int j = 0; j < 4; ++j){
                float s  = fast_tanh(c2[n][j]);
                float fa = attv[j][n] * s;
                float sp  = __shfl_xor(s, 1);
                float fap = __shfl_xor(fa, 1);
                if (!(l & 1)){
                    int row = 16*w + 4*(l>>4) + j;
                    int ci = 8*n + ((l&15) >> 1);
                    sm[A0_FT + row*68 + ci]      = pack_h2f(fa, fap);
                    sm[A0_FT + row*68 + 32 + ci] = pack_h2f(s, sp);
                }
            }
    }
    __syncthreads();  // all waves read all FT rows in P3

    // P3: xg = feat @ Wih0^T  (wave w covers cols {w,w+4,w+8}x16, all 4 m-tiles)
    #pragma unroll
    for (int m = 0; m < 4; ++m){
        uint4 af[4];
        #pragma unroll
        for (int ks = 0; ks < 4; ++ks)
            af[ks] = *reinterpret_cast<const uint4*>(
                sm + A0_FT + (16*m + (l&15))*68 + ks*16 + 4*(l>>4));
        f32x4 acc[3];
        #pragma unroll
        for (int nn = 0; nn < 3; ++nn) acc[nn] = (f32x4){0.f, 0.f, 0.f, 0.f};
        #pragma unroll
        for (int ks = 0; ks < 4; ++ks)
            #pragma unroll
            for (int nn = 0; nn < 3; ++nn)
                acc[nn] = mfma16(af[ks], bw[nn][ks], acc[nn]);
        #pragma unroll
        for (int nn = 0; nn < 3; ++nn)
            #pragma unroll
            for (int j = 0; j < 4; ++j){
                float v = acc[nn][j];
                float vp = __shfl_xor(v, 1);
                if (!(l & 1)){
                    size_t row = (size_t)R0 + 16*m + 4*(l>>4) + j;
                    xgout[row*96 + 8*(w + 4*nn) + ((l&15) >> 1)] = pack_h2f(v, vp);
                }
            }
    }
}

// ---------- kernel 4: xg1 GEMM: out0 @ Wih1^T ----------
__global__ __launch_bounds__(256, 2)
void nbst_xg1(const unsigned* __restrict__ out0g, const float* __restrict__ Wih1,
              unsigned* __restrict__ xgout)
{
    __shared__ u32 sm[64*36];
    const int tid = threadIdx.x;
    const int w = tid >> 6, l = tid & 63;
    const int R0 = blockIdx.x * 64;
    for (int e = tid; e < 64*32; e += 256){
        int row = e >> 5, k = e & 31;
        sm[row*36 + k] = out0g[(size_t)(R0 + row)*32 + k];
    }
    uint4 bw[3][2];
    #pragma unroll
    for (int nn = 0; nn < 3; ++nn)
        #pragma unroll
        for (int ks = 0; ks < 2; ++ks)
            bw[nn][ks] = load_bfrag(Wih1, 64, 16*(w + 4*nn) + (l&15), 32*ks + 8*(l>>4), 64);
    __syncthreads();
    #pragma unroll
    for (int m = 0; m < 4; ++m){
        uint4 af[2];
        #pragma unroll
        for (int ks = 0; ks < 2; ++ks)
            af[ks] = *reinterpret_cast<const uint4*>(
                sm + (16*m + (l&15))*36 + ks*16 + 4*(l>>4));
        f32x4 acc[3];
        #pragma unroll
        for (int nn = 0; nn < 3; ++nn) acc[nn] = (f32x4){0.f, 0.f, 0.f, 0.f};
        #pragma unroll
        for (int ks = 0; ks < 2; ++ks)
            #pragma unroll
            for (int nn = 0; nn < 3; ++nn)
                acc[nn] = mfma16(af[ks], bw[nn][ks], acc[nn]);
        #pragma unroll
        for (int nn = 0; nn < 3; ++nn)
            #pragma unroll
            for (int j = 0; j < 4; ++j){
                float v = acc[nn][j];
                float vp = __shfl_xor(v, 1);
                if (!(l & 1)){
                    size_t row = (size_t)R0 + 16*m + 4*(l>>4) + j;
                    xgout[row*96 + 8*(w + 4*nn) + ((l&15) >> 1)] = pack_h2f(v, vp);
                }
            }
    }
}

// ---------- kernel 3: GRU layer 0 recurrence (xg precomputed) ----------
__global__ __launch_bounds__(256, 2)
void nbst_rec0l(const _Float16* __restrict__ xgh,
                const float* __restrict__ Whh0,
                const float* __restrict__ bih0, const float* __restrict__ bhh0,
                unsigned* __restrict__ out0g, float* __restrict__ hf0g)
{
    __shared__ u32 hp_sm[4*40];
    const int tid = threadIdx.x;
    const int wv = tid >> 6, l = tid & 63;
    const int b = blockIdx.x * 4 + wv;
    u32* HP = hp_sm + wv*40;
    if (l < 32) HP[l] = 0u;

    unsigned whr[32], whz[32], whn[32];
    {
        const float4* p0 = reinterpret_cast<const float4*>(Whh0) + (size_t)l*16;
        const float4* p1 = reinterpret_cast<const float4*>(Whh0) + (size_t)(64+l)*16;
        const float4* p2 = reinterpret_cast<const float4*>(Whh0) + (size_t)(128+l)*16;
        #pragma unroll
        for (int i = 0; i < 16; ++i){
            float4 a = p0[i]; whr[2*i] = pack_h2f(a.x, a.y); whr[2*i+1] = pack_h2f(a.z, a.w);
            float4 c = p1[i]; whz[2*i] = pack_h2f(c.x, c.y); whz[2*i+1] = pack_h2f(c.z, c.w);
            float4 d = p2[i]; whn[2*i] = pack_h2f(d.x, d.y); whn[2*i+1] = pack_h2f(d.z, d.w);
        }
    }
    const float br  = bih0[l]      + bhh0[l];
    const float bz  = bih0[64+l]   + bhh0[64+l];
    const float bxn = bih0[128+l];
    const float bhn = bhh0[128+l];
    float hreg = 0.f;
    const size_t rb = (size_t)b * S_;
    _Float16 xrp = xgh[rb*192 + l];
    _Float16 xzp = xgh[rb*192 + 64 + l];
    _Float16 xnp = xgh[rb*192 + 128 + l];
    wsync();

    #pragma unroll 1
    for (int t = 0; t < S_; ++t){
        float xr = (float)xrp, xz = (float)xzp, xn = (float)xnp;
        {   const size_t bnx = (rb + ((t+1 < S_) ? t+1 : t)) * 192;
            xrp = xgh[bnx + l]; xzp = xgh[bnx + 64 + l]; xnp = xgh[bnx + 128 + l]; }
        float ar = 0.f, az = 0.f, ahn = 0.f;
        #pragma unroll
        for (int k = 0; k < 8; ++k){
            uint4 hv = *reinterpret_cast<const uint4*>(HP + 4*k);
            ar  = dot2h(hv.x, whr[4*k],   ar);  ar  = dot2h(hv.y, whr[4*k+1], ar);
            ar  = dot2h(hv.z, whr[4*k+2], ar);  ar  = dot2h(hv.w, whr[4*k+3], ar);
            az  = dot2h(hv.x, whz[4*k],   az);  az  = dot2h(hv.y, whz[4*k+1], az);
            az  = dot2h(hv.z, whz[4*k+2], az);  az  = dot2h(hv.w, whz[4*k+3], az);
            ahn = dot2h(hv.x, whn[4*k],   ahn); ahn = dot2h(hv.y, whn[4*k+1], ahn);
            ahn = dot2h(hv.z, whn[4*k+2], ahn); ahn = dot2h(hv.w, whn[4*k+3], ahn);
        }
        float rg = fast_sigmoid(xr + ar + br);
        float zg = fast_sigmoid(xz + az + bz);
        float ng = fast_tanh(xn + bxn + rg*(ahn + bhn));
        hreg = (1.f - zg)*ng + zg*hreg;
        float hp2 = __shfl_xor(hreg, 1);
        if (!(l & 1)){
            unsigned hu = pack_h2f(hreg, hp2);
            HP[l >> 1] = hu;
            out0g[(rb + t)*32 + (l >> 1)] = hu;
        }
        wsync();
    }
    hf0g[(size_t)b*64 + l] = hreg;
}

// ---------- kernel 5: GRU layer 1 recurrence + pred head ----------
__global__ __launch_bounds__(256, 2)
void nbst_rec1l(const _Float16* __restrict__ xgh,
                const float* __restrict__ Whh1,
                const float* __restrict__ bih1, const float* __restrict__ bhh1,
                const float* __restrict__ hf0g,
                const float* __restrict__ Wpred, const float* __restrict__ bpred,
                float* __restrict__ outp)
{
    __shared__ u32 hp_sm[4*40];
    const int tid = threadIdx.x;
    const int wv = tid >> 6, l = tid & 63;
    const int b = blockIdx.x * 4 + wv;
    u32* HP = hp_sm + wv*40;
    if (l < 32) HP[l] = 0u;

    unsigned whr[32], whz[32], whn[32];
    {
        const float4* p0 = reinterpret_cast<const float4*>(Whh1) + (size_t)l*16;
        const float4* p1 = reinterpret_cast<const float4*>(Whh1) + (size_t)(64+l)*16;
        const float4* p2 = reinterpret_cast<const float4*>(Whh1) + (size_t)(128+l)*16;
        #pragma unroll
        for (int i = 0; i < 16; ++i){
            float4 a = p0[i]; whr[2*i] = pack_h2f(a.x, a.y); whr[2*i+1] = pack_h2f(a.z, a.w);
            float4 c = p1[i]; whz[2*i] = pack_h2f(c.x, c.y); whz[2*i+1] = pack_h2f(c.z, c.w);
            float4 d = p2[i]; whn[2*i] = pack_h2f(d.x, d.y); whn[2*i+1] = pack_h2f(d.z, d.w);
        }
    }
    const float br  = bih1[l]      + bhh1[l];
    const float bz  = bih1[64+l]   + bhh1[64+l];
    const float bxn = bih1[128+l];
    const float bhn = bhh1[128+l];
    float hreg = 0.f;
    const size_t rb = (size_t)b * S_;
    _Float16 xrp = xgh[rb*192 + l];
    _Float16 xzp = xgh[rb*192 + 64 + l];
    _Float16 xnp = xgh[rb*192 + 128 + l];
    wsync();

    #pragma unroll 1
    for (int t = 0; t < S_; ++t){
        float xr = (float)xrp, xz = (float)xzp, xn = (float)xnp;
        {   const size_t bnx = (rb + ((t+1 < S_) ? t+1 : t)) * 192;
            xrp = xgh[bnx + l]; xzp = xgh[bnx + 64 + l]; xnp = xgh[bnx + 128 + l]; }
        float ar = 0.f, az = 0.f, ahn = 0.f;
        #pragma unroll
        for (int k = 0; k < 8; ++k){
            uint4 hv = *reinterpret_cast<const uint4*>(HP + 4*k);
            ar  = dot2h(hv.x, whr[4*k],   ar);  ar  = dot2h(hv.y, whr[4*k+1], ar);
            ar  = dot2h(hv.z, whr[4*k+2], ar);  ar  = dot2h(hv.w, whr[4*k+3], ar);
            az  = dot2h(hv.x, whz[4*k],   az);  az  = dot2h(hv.y, whz[4*k+1], az);
            az  = dot2h(hv.z, whz[4*k+2], az);  az  = dot2h(hv.w, whz[4*k+3], az);
            ahn = dot2h(hv.x, whn[4*k],   ahn); ahn = dot2h(hv.y, whn[4*k+1], ahn);
            ahn = dot2h(hv.z, whn[4*k+2], ahn); ahn = dot2h(hv.w, whn[4*k+3], ahn);
        }
        float rg = fast_sigmoid(xr + ar + br);
        float zg = fast_sigmoid(xz + az + bz);
        float ng = fast_tanh(xn + bxn + rg*(ahn + bhn));
        hreg = (1.f - zg)*ng + zg*hreg;
        float hp2 = __shfl_xor(hreg, 1);
        if (!(l & 1)) HP[l >> 1] = pack_h2f(hreg, hp2);
        wsync();
    }
    float hf0v = hf0g[(size_t)b*64 + l];
    float part = hf0v * Wpred[l] + hreg * Wpred[64 + l];
    #pragma unroll
    for (int s = 32; s >= 1; s >>= 1) part += __shfl_xor(part, s);
    if (l == 0) outp[b] = fast_tanh(part + bpred[0]);
}

// ---------- launcher ----------
extern "C" void kernel_launch(void* const* d_in, const int* in_sizes, int n_in,
                              void* d_out, int out_size, void* d_ws, size_t ws_size,
                              hipStream_t stream) {
    (void)in_sizes; (void)n_in; (void)out_size; (void)ws_size;
    const float* station_nodes    = (const float*)d_in[1];
    const float* station_features = (const float*)d_in[2];
    const int*   station_emb      = (const int*)d_in[3];
    const float* e0 = (const float*)d_in[4];
    const float* e1 = (const float*)d_in[5];
    const float* e2 = (const float*)d_in[6];
    const float* e3 = (const float*)d_in[7];
    const float* e4 = (const float*)d_in[8];
    const float* W_nodes = (const float*)d_in[9];
    const float* b_nodes = (const float*)d_in[10];
    const float* W_attn  = (const float*)d_in[11];
    const float* W_d1 = (const float*)d_in[13];
    const float* b_d1 = (const float*)d_in[14];
    const float* W_d2 = (const float*)d_in[15];
    const float* b_d2 = (const float*)d_in[16];
    const float* Wih0 = (const float*)d_in[17];
    const float* Whh0 = (const float*)d_in[18];
    const float* bih0 = (const float*)d_in[19];
    const float* bhh0 = (const float*)d_in[20];
    const float* Wih1 = (const float*)d_in[21];
    const float* Whh1 = (const float*)d_in[22];
    const float* bih1 = (const float*)d_in[23];
    const float* bhh1 = (const float*)d_in[24];
    const float* W_pred = (const float*)d_in[25];
    const float* b_pred = (const float*)d_in[26];
    float* outp = (float*)d_out;

    char* ws = (char*)d_ws;
    float*    attnW  = (float*)ws;                        // 512 KiB
    float*    hf0    = (float*)(ws + (1u<<19));           // 512 KiB
    unsigned* out0pk = (unsigned*)(ws + (1u<<20));        // B*S*32 u32 = 44 MB
    unsigned* xg     = (unsigned*)(ws + (48u<<20));       // B*S*96 u32 = 132 MB (f16 pairs)
    const _Float16* xgh = (const _Float16*)xg;

    const int NT = (B_ * S_) / 64;   // 5376 row-tiles

    nbst_attn<<<dim3(512), dim3(256), 0, stream>>>(station_nodes, W_nodes, b_nodes, W_attn, attnW);
    nbst_mlpxg0<<<dim3(NT), dim3(256), 0, stream>>>(
        station_features, station_emb, e0, e1, e2, e3, e4,
        W_d1, b_d1, W_d2, b_d2, Wih0, attnW, xg);
    nbst_rec0l<<<dim3(512), dim3(256), 0, stream>>>(xgh, Whh0, bih0, bhh0, out0pk, hf0);
    nbst_xg1<<<dim3(NT), dim3(256), 0, stream>>>(out0pk, Wih1, xg);
    nbst_rec1l<<<dim3(512), dim3(256), 0, stream>>>(xgh, Whh1, bih1, bhh1, hf0, W_pred, b_pred, outp);
}

// Round 5
// 367.209 us; speedup vs baseline: 3.0153x; 1.3280x over previous
//
#include <hip/hip_runtime.h>
#include <cstdint>
#include <cstddef>

#define B_ 2048
#define S_ 168
#define NT_ 5376   // (B_*S_)/64 row-tiles

// ---------- helpers ----------
typedef _Float16 h2_t __attribute__((ext_vector_type(2)));
typedef _Float16 f16x8 __attribute__((ext_vector_type(8)));
typedef float f32x4 __attribute__((ext_vector_type(4)));
typedef unsigned int u32;

__device__ __forceinline__ float dot2h(unsigned a, unsigned b, float c){
    return __builtin_amdgcn_fdot2(__builtin_bit_cast(h2_t, a),
                                  __builtin_bit_cast(h2_t, b), c, false);
}
__device__ __forceinline__ unsigned pack_h2f(float a, float b){
    h2_t v; v.x = (_Float16)a; v.y = (_Float16)b;
    return __builtin_bit_cast(unsigned, v);
}
__device__ __forceinline__ float fast_exp(float x){
    return __builtin_amdgcn_exp2f(x * 1.44269504088896340736f);
}
__device__ __forceinline__ float fast_sigmoid(float x){
    return __builtin_amdgcn_rcpf(1.0f + fast_exp(-x));
}
__device__ __forceinline__ float fast_tanh(float x){
    return 1.0f - 2.0f * __builtin_amdgcn_rcpf(1.0f + fast_exp(2.0f * x));
}
__device__ __forceinline__ void wsync(){
    asm volatile("s_waitcnt lgkmcnt(0)" ::: "memory");
    __builtin_amdgcn_wave_barrier();
}
__device__ __forceinline__ f32x4 mfma16(uint4 a, uint4 b, f32x4 c){
    return __builtin_amdgcn_mfma_f32_16x16x32_f16(
        __builtin_bit_cast(f16x8, a), __builtin_bit_cast(f16x8, b), c, 0, 0, 0);
}
__device__ __forceinline__ uint4 load_bfrag(const float* __restrict__ W, int ldk,
                                            int o, int kk0, int kmax){
    float w[8];
    #pragma unroll
    for (int e = 0; e < 8; ++e){
        int kk = kk0 + e;
        w[e] = (kk < kmax) ? W[o*ldk + kk] : 0.f;
    }
    uint4 r;
    r.x = pack_h2f(w[0], w[1]); r.y = pack_h2f(w[2], w[3]);
    r.z = pack_h2f(w[4], w[5]); r.w = pack_h2f(w[6], w[7]);
    return r;
}
// function, not macro: '.w' member access must not collide with a macro param
__device__ __forceinline__ void dot4(float& acc, uint4 hv, uint4 wv){
    acc = dot2h(hv.x, wv.x, acc); acc = dot2h(hv.y, wv.y, acc);
    acc = dot2h(hv.z, wv.z, acc); acc = dot2h(hv.w, wv.w, acc);
}

// ---------- kernel 1: attention over stations (proven) ----------
__global__ void nbst_attn(const float* __restrict__ sn, const float* __restrict__ Wn,
                          const float* __restrict__ bn, const float* __restrict__ Wa,
                          float* __restrict__ attnO){
    __shared__ float WnL[64*16];
    __shared__ float WsL[64];
    __shared__ float bnL[64];
    const int tid = threadIdx.x;
    for (int e = tid; e < 1024; e += 256) WnL[e] = Wn[e];
    if (tid < 64){ WsL[tid] = Wa[64 + tid]; bnL[tid] = bn[tid]; }
    __syncthreads();
    const int wv = tid >> 6, l = tid & 63;
    const int b = blockIdx.x * 4 + wv;
    const float* xp = sn + ((size_t)b * 64 + l) * 16;
    float x[16];
    #pragma unroll
    for (int k = 0; k < 16; ++k) x[k] = xp[k];
    float e_i = 0.f;
    for (int h = 0; h < 64; ++h){
        float acc = bnL[h];
        #pragma unroll
        for (int k = 0; k < 16; ++k) acc += x[k] * WnL[h*16 + k];
        e_i += fast_tanh(acc) * WsL[h];
    }
    float m = e_i;
    #pragma unroll
    for (int s = 32; s >= 1; s >>= 1) m = fmaxf(m, __shfl_xor(m, s));
    float p = fast_exp(e_i - m);
    float ssum = p;
    #pragma unroll
    for (int s = 32; s >= 1; s >>= 1) ssum += __shfl_xor(ssum, s);
    attnO[(size_t)b*64 + l] = p * __builtin_amdgcn_rcpf(ssum);
}

// ---------- kernel 2: persistent MLP + xg0 GEMM ----------
#define A0_CAT 0      // [64][36] u32: 0..17 cat pairs, 18..35 zero (K pad)
#define A0_H1  2304   // [64][20]
#define A0_FT  3584   // [64][68]
#define A0_WM  7936   // [8 frags][64 lanes][4]
#define A0_EMB 9984   // 260 f32
#define A0_ATT 10244  // 128 f32: attn rows b0, b0+1
#define A0_TOT 10372

__global__ __launch_bounds__(256, 2)
void nbst_mlpxg0(const float* __restrict__ sf, const int* __restrict__ se,
                 const float* __restrict__ e0, const float* __restrict__ e1,
                 const float* __restrict__ e2, const float* __restrict__ e3,
                 const float* __restrict__ e4,
                 const float* __restrict__ Wd1, const float* __restrict__ bd1,
                 const float* __restrict__ Wd2, const float* __restrict__ bd2,
                 const float* __restrict__ Wih0, const float* __restrict__ attnI,
                 _Float16* __restrict__ xgout)
{
    __shared__ u32 sm[A0_TOT];
    float* smF = reinterpret_cast<float*>(sm);
    const int tid = threadIdx.x;
    const int w = tid >> 6, l = tid & 63;

    // ---- one-time prologue ----
    for (int e = tid; e < 260; e += 256){
        float v;
        if (e < 48)       v = e0[e];
        else if (e < 88)  v = e1[e-48];
        else if (e < 136) v = e2[e-88];
        else if (e < 164) v = e3[e-136];
        else              v = e4[e-164];
        smF[A0_EMB + e] = v;
    }
    for (int f = w; f < 8; f += 4){
        uint4 fr;
        if (f < 4){ int n = f >> 1, ks = f & 1;
                    fr = load_bfrag(Wd1, 36, 16*n + (l&15), 32*ks + 8*(l>>4), 36); }
        else      { int n = f - 4;
                    fr = load_bfrag(Wd2, 32, 16*n + (l&15), 8*(l>>4), 32); }
        *reinterpret_cast<uint4*>(sm + A0_WM + (f*64 + l)*4) = fr;
    }
    uint4 bw[3][4];
    #pragma unroll
    for (int nn = 0; nn < 3; ++nn)
        #pragma unroll
        for (int ks = 0; ks < 4; ++ks)
            bw[nn][ks] = load_bfrag(Wih0, 128, 16*(w + 4*nn) + (l&15), 32*ks + 8*(l>>4), 128);
    for (int e = tid; e < 64*18; e += 256){           // zero CAT K-pad once
        int row = e / 18, j = 18 + e % 18;
        sm[A0_CAT + row*36 + j] = 0u;
    }
    const float bb10 = bd1[(l&15)],  bb11 = bd1[16+(l&15)];
    const float bb20 = bd2[(l&15)],  bb21 = bd2[16+(l&15)];
    const float bb22 = bd2[32+(l&15)], bb23 = bd2[48+(l&15)];
    __syncthreads();

    // ---- persistent tile loop ----
    for (int tile = blockIdx.x; tile < NT_; tile += gridDim.x){
        const int R0 = tile * 64;
        const int b0 = R0 / S_;
        const int eB = (b0 + 1) * S_;
        if (tid < 128){
            int bi = b0 + (tid >> 6); if (bi >= B_) bi = B_ - 1;
            smF[A0_ATT + tid] = attnI[(size_t)bi*64 + (tid & 63)];
        }
        for (int e = tid; e < 64*18; e += 256){
            int row = e / 18, j = e % 18;
            int R = R0 + row;
            float c0, c1;
            if (j < 8){
                c0 = sf[(size_t)R*16 + 2*j]; c1 = sf[(size_t)R*16 + 2*j + 1];
            } else {
                int jj = j - 8, ebl = jj >> 1, d0 = (jj & 1) * 2;
                int idx = se[(size_t)R*5 + ebl] - (ebl >= 2 ? 1 : 0);
                const int toff = (ebl==0)?0:(ebl==1)?48:(ebl==2)?88:(ebl==3)?136:164;
                c0 = smF[A0_EMB + toff + idx*4 + d0];
                c1 = smF[A0_EMB + toff + idx*4 + d0 + 1];
            }
            sm[A0_CAT + row*36 + j] = pack_h2f(c0, c1);
        }
        __syncthreads();

        // P1: h1 = tanh(cat @ Wd1^T + bd1)  (wave w owns m-tile w)
        {
            f32x4 c1a[2];
            c1a[0] = (f32x4){bb10, bb10, bb10, bb10};
            c1a[1] = (f32x4){bb11, bb11, bb11, bb11};
            #pragma unroll
            for (int ks = 0; ks < 2; ++ks){
                uint4 a = *reinterpret_cast<const uint4*>(
                    sm + A0_CAT + (16*w + (l&15))*36 + ks*16 + 4*(l>>4));
                #pragma unroll
                for (int n = 0; n < 2; ++n)
                    c1a[n] = mfma16(a, *reinterpret_cast<const uint4*>(
                        sm + A0_WM + ((n*2 + ks)*64 + l)*4), c1a[n]);
            }
            #pragma unroll
            for (int n = 0; n < 2; ++n)
                #pragma unroll
                for (int j = 0; j < 4; ++j){
                    float v = fast_tanh(c1a[n][j]);
                    float vp = __shfl_xor(v, 1);
                    if (!(l & 1))
                        sm[A0_H1 + (16*w + 4*(l>>4) + j)*20 + 8*n + ((l&15) >> 1)] = pack_h2f(v, vp);
                }
        }
        wsync();

        // P2: sfe = tanh(h1 @ Wd2^T + bd2); feat = [attn*sfe | sfe]
        {
            uint4 a = *reinterpret_cast<const uint4*>(
                sm + A0_H1 + (16*w + (l&15))*20 + 4*(l>>4));
            f32x4 c2[4];
            c2[0] = (f32x4){bb20, bb20, bb20, bb20};
            c2[1] = (f32x4){bb21, bb21, bb21, bb21};
            c2[2] = (f32x4){bb22, bb22, bb22, bb22};
            c2[3] = (f32x4){bb23, bb23, bb23, bb23};
            #pragma unroll
            for (int n = 0; n < 4; ++n)
                c2[n] = mfma16(a, *reinterpret_cast<const uint4*>(
                    sm + A0_WM + ((4 + n)*64 + l)*4), c2[n]);
            #pragma unroll
            for (int n = 0; n < 4; ++n)
                #pragma unroll
                for (int j = 0; j < 4; ++j){
                    int row = 16*w + 4*(l>>4) + j;
                    int rel = (R0 + row >= eB) ? 1 : 0;
                    float s  = fast_tanh(c2[n][j]);
                    float fa = smF[A0_ATT + rel*64 + 16*n + (l&15)] * s;
                    float sp  = __shfl_xor(s, 1);
                    float fap = __shfl_xor(fa, 1);
                    if (!(l & 1)){
                        int ci = 8*n + ((l&15) >> 1);
                        sm[A0_FT + row*68 + ci]      = pack_h2f(fa, fap);
                        sm[A0_FT + row*68 + 32 + ci] = pack_h2f(s, sp);
                    }
                }
        }
        __syncthreads();

        // P3: xg = feat @ Wih0^T ; direct f16 stores
        #pragma unroll
        for (int m = 0; m < 4; ++m){
            uint4 af[4];
            #pragma unroll
            for (int ks = 0; ks < 4; ++ks)
                af[ks] = *reinterpret_cast<const uint4*>(
                    sm + A0_FT + (16*m + (l&15))*68 + ks*16 + 4*(l>>4));
            f32x4 acc[3];
            #pragma unroll
            for (int nn = 0; nn < 3; ++nn) acc[nn] = (f32x4){0.f, 0.f, 0.f, 0.f};
            #pragma unroll
            for (int ks = 0; ks < 4; ++ks)
                #pragma unroll
                for (int nn = 0; nn < 3; ++nn)
                    acc[nn] = mfma16(af[ks], bw[nn][ks], acc[nn]);
            #pragma unroll
            for (int nn = 0; nn < 3; ++nn)
                #pragma unroll
                for (int j = 0; j < 4; ++j){
                    size_t row = (size_t)R0 + 16*m + 4*(l>>4) + j;
                    xgout[row*192 + 16*(w + 4*nn) + (l&15)] = (_Float16)acc[nn][j];
                }
        }
        // next tile's CAT/ATT writes don't touch FT/H1; the post-cat
        // __syncthreads orders P1 of tile i+1 after P3 of tile i.
    }
}

// ---------- kernel 4: persistent xg1 GEMM: out0 @ Wih1^T ----------
__global__ __launch_bounds__(256, 2)
void nbst_xg1(const unsigned* __restrict__ out0g, const float* __restrict__ Wih1,
              _Float16* __restrict__ xgout)
{
    __shared__ u32 sm[64*36];
    const int tid = threadIdx.x;
    const int w = tid >> 6, l = tid & 63;
    uint4 bw[3][2];
    #pragma unroll
    for (int nn = 0; nn < 3; ++nn)
        #pragma unroll
        for (int ks = 0; ks < 2; ++ks)
            bw[nn][ks] = load_bfrag(Wih1, 64, 16*(w + 4*nn) + (l&15), 32*ks + 8*(l>>4), 64);

    for (int tile = blockIdx.x; tile < NT_; tile += gridDim.x){
        const int R0 = tile * 64;
        for (int e = tid; e < 64*32; e += 256){
            int row = e >> 5, k = e & 31;
            sm[row*36 + k] = out0g[(size_t)(R0 + row)*32 + k];
        }
        __syncthreads();
        #pragma unroll
        for (int m = 0; m < 4; ++m){
            uint4 af[2];
            #pragma unroll
            for (int ks = 0; ks < 2; ++ks)
                af[ks] = *reinterpret_cast<const uint4*>(
                    sm + (16*m + (l&15))*36 + ks*16 + 4*(l>>4));
            f32x4 acc[3];
            #pragma unroll
            for (int nn = 0; nn < 3; ++nn) acc[nn] = (f32x4){0.f, 0.f, 0.f, 0.f};
            #pragma unroll
            for (int ks = 0; ks < 2; ++ks)
                #pragma unroll
                for (int nn = 0; nn < 3; ++nn)
                    acc[nn] = mfma16(af[ks], bw[nn][ks], acc[nn]);
            #pragma unroll
            for (int nn = 0; nn < 3; ++nn)
                #pragma unroll
                for (int j = 0; j < 4; ++j){
                    size_t row = (size_t)R0 + 16*m + 4*(l>>4) + j;
                    xgout[row*192 + 16*(w + 4*nn) + (l&15)] = (_Float16)acc[nn][j];
                }
        }
        __syncthreads();   // sm overwritten next tile
    }
}

// ---------- recurrent kernels: weights via LDS -> named regs (forced residency) ----------
#define RW_HP 6912    // per-wave h pairs, stride 40

__global__ __launch_bounds__(256, 2)
void nbst_rec0l(const _Float16* __restrict__ xgh, const float* __restrict__ Whh0,
                const float* __restrict__ bih0, const float* __restrict__ bhh0,
                unsigned* __restrict__ out0g, float* __restrict__ hf0g)
{
    __shared__ u32 smr[RW_HP + 4*40];
    const int tid = threadIdx.x, wv = tid >> 6, l = tid & 63;
    const int b = blockIdx.x * 4 + wv;
    for (int e = tid; e < 192*32; e += 256){
        int row = e >> 5, k = e & 31;
        smr[row*36 + k] = pack_h2f(Whh0[row*64 + 2*k], Whh0[row*64 + 2*k + 1]);
    }
    u32* HP = smr + RW_HP + wv*40;
    if (l < 32) HP[l] = 0u;
    __syncthreads();
    uint4 wr0,wr1,wr2,wr3,wr4,wr5,wr6,wr7;
    uint4 wz0,wz1,wz2,wz3,wz4,wz5,wz6,wz7;
    uint4 wn0,wn1,wn2,wn3,wn4,wn5,wn6,wn7;
    {
        const u32* pr = smr + l*36;
        const u32* pz = smr + (64+l)*36;
        const u32* pn = smr + (128+l)*36;
        wr0 = *(const uint4*)(pr+0);  wr1 = *(const uint4*)(pr+4);
        wr2 = *(const uint4*)(pr+8);  wr3 = *(const uint4*)(pr+12);
        wr4 = *(const uint4*)(pr+16); wr5 = *(const uint4*)(pr+20);
        wr6 = *(const uint4*)(pr+24); wr7 = *(const uint4*)(pr+28);
        wz0 = *(const uint4*)(pz+0);  wz1 = *(const uint4*)(pz+4);
        wz2 = *(const uint4*)(pz+8);  wz3 = *(const uint4*)(pz+12);
        wz4 = *(const uint4*)(pz+16); wz5 = *(const uint4*)(pz+20);
        wz6 = *(const uint4*)(pz+24); wz7 = *(const uint4*)(pz+28);
        wn0 = *(const uint4*)(pn+0);  wn1 = *(const uint4*)(pn+4);
        wn2 = *(const uint4*)(pn+8);  wn3 = *(const uint4*)(pn+12);
        wn4 = *(const uint4*)(pn+16); wn5 = *(const uint4*)(pn+20);
        wn6 = *(const uint4*)(pn+24); wn7 = *(const uint4*)(pn+28);
    }
    const float br  = bih0[l]      + bhh0[l];
    const float bz  = bih0[64+l]   + bhh0[64+l];
    const float bxn = bih0[128+l];
    const float bhn = bhh0[128+l];
    float hreg = 0.f;
    const size_t rb = (size_t)b * S_;
    const _Float16* x0 = xgh + rb*192;
    _Float16 xra = x0[l],     xza = x0[64+l],     xna = x0[128+l];
    _Float16 xrb = x0[192+l], xzb = x0[192+64+l], xnb = x0[192+128+l];
    wsync();

    #pragma unroll 1
    for (int t = 0; t < S_; ++t){
        float xr = (float)xra, xz = (float)xza, xn = (float)xna;
        xra = xrb; xza = xzb; xna = xnb;
        {   int tn = (t + 2 < S_) ? t + 2 : S_ - 1;
            const _Float16* q = xgh + (rb + tn)*192;
            xrb = q[l]; xzb = q[64+l]; xnb = q[128+l]; }
        uint4 h0 = *(const uint4*)(HP+0);  uint4 h1 = *(const uint4*)(HP+4);
        uint4 h2 = *(const uint4*)(HP+8);  uint4 h3 = *(const uint4*)(HP+12);
        uint4 h4 = *(const uint4*)(HP+16); uint4 h5 = *(const uint4*)(HP+20);
        uint4 h6 = *(const uint4*)(HP+24); uint4 h7 = *(const uint4*)(HP+28);
        float ar0=0,az0=0,an0=0,ar1=0,az1=0,an1=0;
        dot4(ar0,h0,wr0); dot4(az0,h0,wz0); dot4(an0,h0,wn0);
        dot4(ar1,h1,wr1); dot4(az1,h1,wz1); dot4(an1,h1,wn1);
        dot4(ar0,h2,wr2); dot4(az0,h2,wz2); dot4(an0,h2,wn2);
        dot4(ar1,h3,wr3); dot4(az1,h3,wz3); dot4(an1,h3,wn3);
        dot4(ar0,h4,wr4); dot4(az0,h4,wz4); dot4(an0,h4,wn4);
        dot4(ar1,h5,wr5); dot4(az1,h5,wz5); dot4(an1,h5,wn5);
        dot4(ar0,h6,wr6); dot4(az0,h6,wz6); dot4(an0,h6,wn6);
        dot4(ar1,h7,wr7); dot4(az1,h7,wz7); dot4(an1,h7,wn7);
        float rg = fast_sigmoid(xr + ar0 + ar1 + br);
        float zg = fast_sigmoid(xz + az0 + az1 + bz);
        float ng = fast_tanh(xn + bxn + rg*(an0 + an1 + bhn));
        hreg = (1.f - zg)*ng + zg*hreg;
        float hp2 = __shfl_xor(hreg, 1);
        if (!(l & 1)){
            unsigned hu = pack_h2f(hreg, hp2);
            HP[l >> 1] = hu;
            out0g[(rb + t)*32 + (l >> 1)] = hu;
        }
        wsync();
    }
    hf0g[(size_t)b*64 + l] = hreg;
}

__global__ __launch_bounds__(256, 2)
void nbst_rec1l(const _Float16* __restrict__ xgh, const float* __restrict__ Whh1,
                const float* __restrict__ bih1, const float* __restrict__ bhh1,
                const float* __restrict__ hf0g,
                const float* __restrict__ Wpred, const float* __restrict__ bpred,
                float* __restrict__ outp)
{
    __shared__ u32 smr[RW_HP + 4*40];
    const int tid = threadIdx.x, wv = tid >> 6, l = tid & 63;
    const int b = blockIdx.x * 4 + wv;
    for (int e = tid; e < 192*32; e += 256){
        int row = e >> 5, k = e & 31;
        smr[row*36 + k] = pack_h2f(Whh1[row*64 + 2*k], Whh1[row*64 + 2*k + 1]);
    }
    u32* HP = smr + RW_HP + wv*40;
    if (l < 32) HP[l] = 0u;
    __syncthreads();
    uint4 wr0,wr1,wr2,wr3,wr4,wr5,wr6,wr7;
    uint4 wz0,wz1,wz2,wz3,wz4,wz5,wz6,wz7;
    uint4 wn0,wn1,wn2,wn3,wn4,wn5,wn6,wn7;
    {
        const u32* pr = smr + l*36;
        const u32* pz = smr + (64+l)*36;
        const u32* pn = smr + (128+l)*36;
        wr0 = *(const uint4*)(pr+0);  wr1 = *(const uint4*)(pr+4);
        wr2 = *(const uint4*)(pr+8);  wr3 = *(const uint4*)(pr+12);
        wr4 = *(const uint4*)(pr+16); wr5 = *(const uint4*)(pr+20);
        wr6 = *(const uint4*)(pr+24); wr7 = *(const uint4*)(pr+28);
        wz0 = *(const uint4*)(pz+0);  wz1 = *(const uint4*)(pz+4);
        wz2 = *(const uint4*)(pz+8);  wz3 = *(const uint4*)(pz+12);
        wz4 = *(const uint4*)(pz+16); wz5 = *(const uint4*)(pz+20);
        wz6 = *(const uint4*)(pz+24); wz7 = *(const uint4*)(pz+28);
        wn0 = *(const uint4*)(pn+0);  wn1 = *(const uint4*)(pn+4);
        wn2 = *(const uint4*)(pn+8);  wn3 = *(const uint4*)(pn+12);
        wn4 = *(const uint4*)(pn+16); wn5 = *(const uint4*)(pn+20);
        wn6 = *(const uint4*)(pn+24); wn7 = *(const uint4*)(pn+28);
    }
    const float br  = bih1[l]      + bhh1[l];
    const float bz  = bih1[64+l]   + bhh1[64+l];
    const float bxn = bih1[128+l];
    const float bhn = bhh1[128+l];
    float hreg = 0.f;
    const size_t rb = (size_t)b * S_;
    const _Float16* x0 = xgh + rb*192;
    _Float16 xra = x0[l],     xza = x0[64+l],     xna = x0[128+l];
    _Float16 xrb = x0[192+l], xzb = x0[192+64+l], xnb = x0[192+128+l];
    wsync();

    #pragma unroll 1
    for (int t = 0; t < S_; ++t){
        float xr = (float)xra, xz = (float)xza, xn = (float)xna;
        xra = xrb; xza = xzb; xna = xnb;
        {   int tn = (t + 2 < S_) ? t + 2 : S_ - 1;
            const _Float16* q = xgh + (rb + tn)*192;
            xrb = q[l]; xzb = q[64+l]; xnb = q[128+l]; }
        uint4 h0 = *(const uint4*)(HP+0);  uint4 h1 = *(const uint4*)(HP+4);
        uint4 h2 = *(const uint4*)(HP+8);  uint4 h3 = *(const uint4*)(HP+12);
        uint4 h4 = *(const uint4*)(HP+16); uint4 h5 = *(const uint4*)(HP+20);
        uint4 h6 = *(const uint4*)(HP+24); uint4 h7 = *(const uint4*)(HP+28);
        float ar0=0,az0=0,an0=0,ar1=0,az1=0,an1=0;
        dot4(ar0,h0,wr0); dot4(az0,h0,wz0); dot4(an0,h0,wn0);
        dot4(ar1,h1,wr1); dot4(az1,h1,wz1); dot4(an1,h1,wn1);
        dot4(ar0,h2,wr2); dot4(az0,h2,wz2); dot4(an0,h2,wn2);
        dot4(ar1,h3,wr3); dot4(az1,h3,wz3); dot4(an1,h3,wn3);
        dot4(ar0,h4,wr4); dot4(az0,h4,wz4); dot4(an0,h4,wn4);
        dot4(ar1,h5,wr5); dot4(az1,h5,wz5); dot4(an1,h5,wn5);
        dot4(ar0,h6,wr6); dot4(az0,h6,wz6); dot4(an0,h6,wn6);
        dot4(ar1,h7,wr7); dot4(az1,h7,wz7); dot4(an1,h7,wn7);
        float rg = fast_sigmoid(xr + ar0 + ar1 + br);
        float zg = fast_sigmoid(xz + az0 + az1 + bz);
        float ng = fast_tanh(xn + bxn + rg*(an0 + an1 + bhn));
        hreg = (1.f - zg)*ng + zg*hreg;
        float hp2 = __shfl_xor(hreg, 1);
        if (!(l & 1)) HP[l >> 1] = pack_h2f(hreg, hp2);
        wsync();
    }
    float hf0v = hf0g[(size_t)b*64 + l];
    float part = hf0v * Wpred[l] + hreg * Wpred[64 + l];
    #pragma unroll
    for (int s = 32; s >= 1; s >>= 1) part += __shfl_xor(part, s);
    if (l == 0) outp[b] = fast_tanh(part + bpred[0]);
}

// ---------- launcher ----------
extern "C" void kernel_launch(void* const* d_in, const int* in_sizes, int n_in,
                              void* d_out, int out_size, void* d_ws, size_t ws_size,
                              hipStream_t stream) {
    (void)in_sizes; (void)n_in; (void)out_size; (void)ws_size;
    const float* station_nodes    = (const float*)d_in[1];
    const float* station_features = (const float*)d_in[2];
    const int*   station_emb      = (const int*)d_in[3];
    const float* e0 = (const float*)d_in[4];
    const float* e1 = (const float*)d_in[5];
    const float* e2 = (const float*)d_in[6];
    const float* e3 = (const float*)d_in[7];
    const float* e4 = (const float*)d_in[8];
    const float* W_nodes = (const float*)d_in[9];
    const float* b_nodes = (const float*)d_in[10];
    const float* W_attn  = (const float*)d_in[11];
    const float* W_d1 = (const float*)d_in[13];
    const float* b_d1 = (const float*)d_in[14];
    const float* W_d2 = (const float*)d_in[15];
    const float* b_d2 = (const float*)d_in[16];
    const float* Wih0 = (const float*)d_in[17];
    const float* Whh0 = (const float*)d_in[18];
    const float* bih0 = (const float*)d_in[19];
    const float* bhh0 = (const float*)d_in[20];
    const float* Wih1 = (const float*)d_in[21];
    const float* Whh1 = (const float*)d_in[22];
    const float* bih1 = (const float*)d_in[23];
    const float* bhh1 = (const float*)d_in[24];
    const float* W_pred = (const float*)d_in[25];
    const float* b_pred = (const float*)d_in[26];
    float* outp = (float*)d_out;

    char* ws = (char*)d_ws;
    float*    attnW  = (float*)ws;                        // 512 KiB
    float*    hf0    = (float*)(ws + (1u<<19));           // 512 KiB
    unsigned* out0pk = (unsigned*)(ws + (1u<<20));        // B*S*32 u32 = 44 MB
    _Float16* xg16   = (_Float16*)(ws + (48u<<20));       // B*S*192 f16 = 132 MB
    const _Float16* xgh = (const _Float16*)xg16;

    nbst_attn<<<dim3(512), dim3(256), 0, stream>>>(station_nodes, W_nodes, b_nodes, W_attn, attnW);
    nbst_mlpxg0<<<dim3(768), dim3(256), 0, stream>>>(
        station_features, station_emb, e0, e1, e2, e3, e4,
        W_d1, b_d1, W_d2, b_d2, Wih0, attnW, xg16);
    nbst_rec0l<<<dim3(512), dim3(256), 0, stream>>>(xgh, Whh0, bih0, bhh0, out0pk, hf0);
    nbst_xg1<<<dim3(1024), dim3(256), 0, stream>>>(out0pk, Wih1, xg16);
    nbst_rec1l<<<dim3(512), dim3(256), 0, stream>>>(xgh, Whh1, bih1, bhh1, hf0, W_pred, b_pred, outp);
}

// Round 6
// 365.502 us; speedup vs baseline: 3.0294x; 1.0047x over previous
//
#include <hip/hip_runtime.h>
#include <cstdint>
#include <cstddef>

#define B_ 2048
#define S_ 168
#define NT_ 5376   // (B_*S_)/64 row-tiles

// ---------- helpers ----------
typedef _Float16 h2_t __attribute__((ext_vector_type(2)));
typedef _Float16 f16x8 __attribute__((ext_vector_type(8)));
typedef float f32x4 __attribute__((ext_vector_type(4)));
typedef unsigned int u32;

__device__ __forceinline__ float dot2h(unsigned a, unsigned b, float c){
    return __builtin_amdgcn_fdot2(__builtin_bit_cast(h2_t, a),
                                  __builtin_bit_cast(h2_t, b), c, false);
}
__device__ __forceinline__ unsigned pack_h2f(float a, float b){
    h2_t v; v.x = (_Float16)a; v.y = (_Float16)b;
    return __builtin_bit_cast(unsigned, v);
}
__device__ __forceinline__ float fast_exp(float x){
    return __builtin_amdgcn_exp2f(x * 1.44269504088896340736f);
}
__device__ __forceinline__ float fast_sigmoid(float x){
    return __builtin_amdgcn_rcpf(1.0f + fast_exp(-x));
}
__device__ __forceinline__ float fast_tanh(float x){
    return 1.0f - 2.0f * __builtin_amdgcn_rcpf(1.0f + fast_exp(2.0f * x));
}
__device__ __forceinline__ void wsync(){
    asm volatile("s_waitcnt lgkmcnt(0)" ::: "memory");
    __builtin_amdgcn_wave_barrier();
}
__device__ __forceinline__ f32x4 mfma16(uint4 a, uint4 b, f32x4 c){
    return __builtin_amdgcn_mfma_f32_16x16x32_f16(
        __builtin_bit_cast(f16x8, a), __builtin_bit_cast(f16x8, b), c, 0, 0, 0);
}
__device__ __forceinline__ uint4 load_bfrag(const float* __restrict__ W, int ldk,
                                            int o, int kk0, int kmax){
    float w[8];
    #pragma unroll
    for (int e = 0; e < 8; ++e){
        int kk = kk0 + e;
        w[e] = (kk < kmax) ? W[o*ldk + kk] : 0.f;
    }
    uint4 r;
    r.x = pack_h2f(w[0], w[1]); r.y = pack_h2f(w[2], w[3]);
    r.z = pack_h2f(w[4], w[5]); r.w = pack_h2f(w[6], w[7]);
    return r;
}

// ---------- kernel 1: attention over stations (proven) ----------
__global__ void nbst_attn(const float* __restrict__ sn, const float* __restrict__ Wn,
                          const float* __restrict__ bn, const float* __restrict__ Wa,
                          float* __restrict__ attnO){
    __shared__ float WnL[64*16];
    __shared__ float WsL[64];
    __shared__ float bnL[64];
    const int tid = threadIdx.x;
    for (int e = tid; e < 1024; e += 256) WnL[e] = Wn[e];
    if (tid < 64){ WsL[tid] = Wa[64 + tid]; bnL[tid] = bn[tid]; }
    __syncthreads();
    const int wv = tid >> 6, l = tid & 63;
    const int b = blockIdx.x * 4 + wv;
    const float* xp = sn + ((size_t)b * 64 + l) * 16;
    float x[16];
    #pragma unroll
    for (int k = 0; k < 16; ++k) x[k] = xp[k];
    float e_i = 0.f;
    for (int h = 0; h < 64; ++h){
        float acc = bnL[h];
        #pragma unroll
        for (int k = 0; k < 16; ++k) acc += x[k] * WnL[h*16 + k];
        e_i += fast_tanh(acc) * WsL[h];
    }
    float m = e_i;
    #pragma unroll
    for (int s = 32; s >= 1; s >>= 1) m = fmaxf(m, __shfl_xor(m, s));
    float p = fast_exp(e_i - m);
    float ssum = p;
    #pragma unroll
    for (int s = 32; s >= 1; s >>= 1) ssum += __shfl_xor(ssum, s);
    attnO[(size_t)b*64 + l] = p * __builtin_amdgcn_rcpf(ssum);
}

// ---------- kernel 2: persistent MLP + xg0 GEMM (proven round 5) ----------
#define A0_CAT 0      // [64][36] u32: 0..17 cat pairs, 18..35 zero (K pad)
#define A0_H1  2304   // [64][20]
#define A0_FT  3584   // [64][68]
#define A0_WM  7936   // [8 frags][64 lanes][4]
#define A0_EMB 9984   // 260 f32
#define A0_ATT 10244  // 128 f32: attn rows b0, b0+1
#define A0_TOT 10372

__global__ __launch_bounds__(256, 2)
void nbst_mlpxg0(const float* __restrict__ sf, const int* __restrict__ se,
                 const float* __restrict__ e0, const float* __restrict__ e1,
                 const float* __restrict__ e2, const float* __restrict__ e3,
                 const float* __restrict__ e4,
                 const float* __restrict__ Wd1, const float* __restrict__ bd1,
                 const float* __restrict__ Wd2, const float* __restrict__ bd2,
                 const float* __restrict__ Wih0, const float* __restrict__ attnI,
                 _Float16* __restrict__ xgout)
{
    __shared__ u32 sm[A0_TOT];
    float* smF = reinterpret_cast<float*>(sm);
    const int tid = threadIdx.x;
    const int w = tid >> 6, l = tid & 63;

    // ---- one-time prologue ----
    for (int e = tid; e < 260; e += 256){
        float v;
        if (e < 48)       v = e0[e];
        else if (e < 88)  v = e1[e-48];
        else if (e < 136) v = e2[e-88];
        else if (e < 164) v = e3[e-136];
        else              v = e4[e-164];
        smF[A0_EMB + e] = v;
    }
    for (int f = w; f < 8; f += 4){
        uint4 fr;
        if (f < 4){ int n = f >> 1, ks = f & 1;
                    fr = load_bfrag(Wd1, 36, 16*n + (l&15), 32*ks + 8*(l>>4), 36); }
        else      { int n = f - 4;
                    fr = load_bfrag(Wd2, 32, 16*n + (l&15), 8*(l>>4), 32); }
        *reinterpret_cast<uint4*>(sm + A0_WM + (f*64 + l)*4) = fr;
    }
    uint4 bw[3][4];
    #pragma unroll
    for (int nn = 0; nn < 3; ++nn)
        #pragma unroll
        for (int ks = 0; ks < 4; ++ks)
            bw[nn][ks] = load_bfrag(Wih0, 128, 16*(w + 4*nn) + (l&15), 32*ks + 8*(l>>4), 128);
    for (int e = tid; e < 64*18; e += 256){           // zero CAT K-pad once
        int row = e / 18, j = 18 + e % 18;
        sm[A0_CAT + row*36 + j] = 0u;
    }
    const float bb10 = bd1[(l&15)],  bb11 = bd1[16+(l&15)];
    const float bb20 = bd2[(l&15)],  bb21 = bd2[16+(l&15)];
    const float bb22 = bd2[32+(l&15)], bb23 = bd2[48+(l&15)];
    __syncthreads();

    // ---- persistent tile loop ----
    for (int tile = blockIdx.x; tile < NT_; tile += gridDim.x){
        const int R0 = tile * 64;
        const int b0 = R0 / S_;
        const int eB = (b0 + 1) * S_;
        if (tid < 128){
            int bi = b0 + (tid >> 6); if (bi >= B_) bi = B_ - 1;
            smF[A0_ATT + tid] = attnI[(size_t)bi*64 + (tid & 63)];
        }
        for (int e = tid; e < 64*18; e += 256){
            int row = e / 18, j = e % 18;
            int R = R0 + row;
            float c0, c1;
            if (j < 8){
                c0 = sf[(size_t)R*16 + 2*j]; c1 = sf[(size_t)R*16 + 2*j + 1];
            } else {
                int jj = j - 8, ebl = jj >> 1, d0 = (jj & 1) * 2;
                int idx = se[(size_t)R*5 + ebl] - (ebl >= 2 ? 1 : 0);
                const int toff = (ebl==0)?0:(ebl==1)?48:(ebl==2)?88:(ebl==3)?136:164;
                c0 = smF[A0_EMB + toff + idx*4 + d0];
                c1 = smF[A0_EMB + toff + idx*4 + d0 + 1];
            }
            sm[A0_CAT + row*36 + j] = pack_h2f(c0, c1);
        }
        __syncthreads();

        // P1: h1 = tanh(cat @ Wd1^T + bd1)
        {
            f32x4 c1a[2];
            c1a[0] = (f32x4){bb10, bb10, bb10, bb10};
            c1a[1] = (f32x4){bb11, bb11, bb11, bb11};
            #pragma unroll
            for (int ks = 0; ks < 2; ++ks){
                uint4 a = *reinterpret_cast<const uint4*>(
                    sm + A0_CAT + (16*w + (l&15))*36 + ks*16 + 4*(l>>4));
                #pragma unroll
                for (int n = 0; n < 2; ++n)
                    c1a[n] = mfma16(a, *reinterpret_cast<const uint4*>(
                        sm + A0_WM + ((n*2 + ks)*64 + l)*4), c1a[n]);
            }
            #pragma unroll
            for (int n = 0; n < 2; ++n)
                #pragma unroll
                for (int j = 0; j < 4; ++j){
                    float v = fast_tanh(c1a[n][j]);
                    float vp = __shfl_xor(v, 1);
                    if (!(l & 1))
                        sm[A0_H1 + (16*w + 4*(l>>4) + j)*20 + 8*n + ((l&15) >> 1)] = pack_h2f(v, vp);
                }
        }
        wsync();

        // P2: sfe = tanh(h1 @ Wd2^T + bd2); feat = [attn*sfe | sfe]
        {
            uint4 a = *reinterpret_cast<const uint4*>(
                sm + A0_H1 + (16*w + (l&15))*20 + 4*(l>>4));
            f32x4 c2[4];
            c2[0] = (f32x4){bb20, bb20, bb20, bb20};
            c2[1] = (f32x4){bb21, bb21, bb21, bb21};
            c2[2] = (f32x4){bb22, bb22, bb22, bb22};
            c2[3] = (f32x4){bb23, bb23, bb23, bb23};
            #pragma unroll
            for (int n = 0; n < 4; ++n)
                c2[n] = mfma16(a, *reinterpret_cast<const uint4*>(
                    sm + A0_WM + ((4 + n)*64 + l)*4), c2[n]);
            #pragma unroll
            for (int n = 0; n < 4; ++n)
                #pragma unroll
                for (int j = 0; j < 4; ++j){
                    int row = 16*w + 4*(l>>4) + j;
                    int rel = (R0 + row >= eB) ? 1 : 0;
                    float s  = fast_tanh(c2[n][j]);
                    float fa = smF[A0_ATT + rel*64 + 16*n + (l&15)] * s;
                    float sp  = __shfl_xor(s, 1);
                    float fap = __shfl_xor(fa, 1);
                    if (!(l & 1)){
                        int ci = 8*n + ((l&15) >> 1);
                        sm[A0_FT + row*68 + ci]      = pack_h2f(fa, fap);
                        sm[A0_FT + row*68 + 32 + ci] = pack_h2f(s, sp);
                    }
                }
        }
        __syncthreads();

        // P3: xg = feat @ Wih0^T ; direct f16 stores
        #pragma unroll
        for (int m = 0; m < 4; ++m){
            uint4 af[4];
            #pragma unroll
            for (int ks = 0; ks < 4; ++ks)
                af[ks] = *reinterpret_cast<const uint4*>(
                    sm + A0_FT + (16*m + (l&15))*68 + ks*16 + 4*(l>>4));
            f32x4 acc[3];
            #pragma unroll
            for (int nn = 0; nn < 3; ++nn) acc[nn] = (f32x4){0.f, 0.f, 0.f, 0.f};
            #pragma unroll
            for (int ks = 0; ks < 4; ++ks)
                #pragma unroll
                for (int nn = 0; nn < 3; ++nn)
                    acc[nn] = mfma16(af[ks], bw[nn][ks], acc[nn]);
            #pragma unroll
            for (int nn = 0; nn < 3; ++nn)
                #pragma unroll
                for (int j = 0; j < 4; ++j){
                    size_t row = (size_t)R0 + 16*m + 4*(l>>4) + j;
                    xgout[row*192 + 16*(w + 4*nn) + (l&15)] = (_Float16)acc[nn][j];
                }
        }
    }
}

// ---------- kernel 4: persistent xg1 GEMM: out0 @ Wih1^T ----------
__global__ __launch_bounds__(256, 2)
void nbst_xg1(const unsigned* __restrict__ out0g, const float* __restrict__ Wih1,
              _Float16* __restrict__ xgout)
{
    __shared__ u32 sm[64*36];
    const int tid = threadIdx.x;
    const int w = tid >> 6, l = tid & 63;
    uint4 bw[3][2];
    #pragma unroll
    for (int nn = 0; nn < 3; ++nn)
        #pragma unroll
        for (int ks = 0; ks < 2; ++ks)
            bw[nn][ks] = load_bfrag(Wih1, 64, 16*(w + 4*nn) + (l&15), 32*ks + 8*(l>>4), 64);

    for (int tile = blockIdx.x; tile < NT_; tile += gridDim.x){
        const int R0 = tile * 64;
        for (int e = tid; e < 64*32; e += 256){
            int row = e >> 5, k = e & 31;
            sm[row*36 + k] = out0g[(size_t)(R0 + row)*32 + k];
        }
        __syncthreads();
        #pragma unroll
        for (int m = 0; m < 4; ++m){
            uint4 af[2];
            #pragma unroll
            for (int ks = 0; ks < 2; ++ks)
                af[ks] = *reinterpret_cast<const uint4*>(
                    sm + (16*m + (l&15))*36 + ks*16 + 4*(l>>4));
            f32x4 acc[3];
            #pragma unroll
            for (int nn = 0; nn < 3; ++nn) acc[nn] = (f32x4){0.f, 0.f, 0.f, 0.f};
            #pragma unroll
            for (int ks = 0; ks < 2; ++ks)
                #pragma unroll
                for (int nn = 0; nn < 3; ++nn)
                    acc[nn] = mfma16(af[ks], bw[nn][ks], acc[nn]);
            #pragma unroll
            for (int nn = 0; nn < 3; ++nn)
                #pragma unroll
                for (int j = 0; j < 4; ++j){
                    size_t row = (size_t)R0 + 16*m + 4*(l>>4) + j;
                    xgout[row*192 + 16*(w + 4*nn) + (l&15)] = (_Float16)acc[nn][j];
                }
        }
        __syncthreads();
    }
}

// ---------- recurrent kernels: asm-pinned weight registers ----------
#define RW_HP 6912    // per-wave h pairs, stride 40

__global__ __launch_bounds__(256, 2)
void nbst_rec0l(const _Float16* __restrict__ xgh, const float* __restrict__ Whh0,
                const float* __restrict__ bih0, const float* __restrict__ bhh0,
                unsigned* __restrict__ out0g, float* __restrict__ hf0g)
{
    __shared__ u32 smr[RW_HP + 4*40];
    const int tid = threadIdx.x, wv = tid >> 6, l = tid & 63;
    const int b = blockIdx.x * 4 + wv;
    for (int e = tid; e < 192*32; e += 256){
        int row = e >> 5, k = e & 31;
        smr[row*36 + k] = pack_h2f(Whh0[row*64 + 2*k], Whh0[row*64 + 2*k + 1]);
    }
    u32* HP = smr + RW_HP + wv*40;
    if (l < 32) HP[l] = 0u;
    __syncthreads();

    u32 wr[32], wz[32], wn[32];
    {
        const u32* pr = smr + l*36;
        const u32* pz = smr + (64+l)*36;
        const u32* pn = smr + (128+l)*36;
        #pragma unroll
        for (int i = 0; i < 8; ++i){
            uint4 a = *(const uint4*)(pr + 4*i);
            wr[4*i] = a.x; wr[4*i+1] = a.y; wr[4*i+2] = a.z; wr[4*i+3] = a.w;
            uint4 c = *(const uint4*)(pz + 4*i);
            wz[4*i] = c.x; wz[4*i+1] = c.y; wz[4*i+2] = c.z; wz[4*i+3] = c.w;
            uint4 d = *(const uint4*)(pn + 4*i);
            wn[4*i] = d.x; wn[4*i+1] = d.y; wn[4*i+2] = d.z; wn[4*i+3] = d.w;
        }
    }
    // make the 96 weight values opaque: compiler cannot rematerialize them
    // from LDS inside the loop -> forced VGPR residency.
    #pragma unroll
    for (int i = 0; i < 32; ++i)
        asm volatile("" : "+v"(wr[i]), "+v"(wz[i]), "+v"(wn[i]));

    const float br  = bih0[l]      + bhh0[l];
    const float bz  = bih0[64+l]   + bhh0[64+l];
    const float bxn = bih0[128+l];
    const float bhn = bhh0[128+l];
    float hreg = 0.f;
    const size_t rb = (size_t)b * S_;
    const _Float16* x0 = xgh + rb*192;
    _Float16 xra = x0[l],     xza = x0[64+l],     xna = x0[128+l];
    _Float16 xrb = x0[192+l], xzb = x0[192+64+l], xnb = x0[192+128+l];
    wsync();

    #pragma unroll 1
    for (int t = 0; t < S_; ++t){
        float xr = (float)xra, xz = (float)xza, xn = (float)xna;
        xra = xrb; xza = xzb; xna = xnb;
        {   int tn = (t + 2 < S_) ? t + 2 : S_ - 1;
            const _Float16* q = xgh + (rb + tn)*192;
            xrb = q[l]; xzb = q[64+l]; xnb = q[128+l]; }
        float ar0=0,az0=0,an0=0,ar1=0,az1=0,an1=0;
        #pragma unroll
        for (int k = 0; k < 8; ++k){
            uint4 hv = *(const uint4*)(HP + 4*k);
            float& ar = (k & 1) ? ar1 : ar0;
            float& az = (k & 1) ? az1 : az0;
            float& an = (k & 1) ? an1 : an0;
            ar = dot2h(hv.x, wr[4*k],   ar); ar = dot2h(hv.y, wr[4*k+1], ar);
            ar = dot2h(hv.z, wr[4*k+2], ar); ar = dot2h(hv.w, wr[4*k+3], ar);
            az = dot2h(hv.x, wz[4*k],   az); az = dot2h(hv.y, wz[4*k+1], az);
            az = dot2h(hv.z, wz[4*k+2], az); az = dot2h(hv.w, wz[4*k+3], az);
            an = dot2h(hv.x, wn[4*k],   an); an = dot2h(hv.y, wn[4*k+1], an);
            an = dot2h(hv.z, wn[4*k+2], an); an = dot2h(hv.w, wn[4*k+3], an);
        }
        float rg = fast_sigmoid(xr + ar0 + ar1 + br);
        float zg = fast_sigmoid(xz + az0 + az1 + bz);
        float ng = fast_tanh(xn + bxn + rg*(an0 + an1 + bhn));
        hreg = (1.f - zg)*ng + zg*hreg;
        float hp2 = __shfl_xor(hreg, 1);
        if (!(l & 1)){
            unsigned hu = pack_h2f(hreg, hp2);
            HP[l >> 1] = hu;
            out0g[(rb + t)*32 + (l >> 1)] = hu;
        }
        wsync();
    }
    hf0g[(size_t)b*64 + l] = hreg;
}

__global__ __launch_bounds__(256, 2)
void nbst_rec1l(const _Float16* __restrict__ xgh, const float* __restrict__ Whh1,
                const float* __restrict__ bih1, const float* __restrict__ bhh1,
                const float* __restrict__ hf0g,
                const float* __restrict__ Wpred, const float* __restrict__ bpred,
                float* __restrict__ outp)
{
    __shared__ u32 smr[RW_HP + 4*40];
    const int tid = threadIdx.x, wv = tid >> 6, l = tid & 63;
    const int b = blockIdx.x * 4 + wv;
    for (int e = tid; e < 192*32; e += 256){
        int row = e >> 5, k = e & 31;
        smr[row*36 + k] = pack_h2f(Whh1[row*64 + 2*k], Whh1[row*64 + 2*k + 1]);
    }
    u32* HP = smr + RW_HP + wv*40;
    if (l < 32) HP[l] = 0u;
    __syncthreads();

    u32 wr[32], wz[32], wn[32];
    {
        const u32* pr = smr + l*36;
        const u32* pz = smr + (64+l)*36;
        const u32* pn = smr + (128+l)*36;
        #pragma unroll
        for (int i = 0; i < 8; ++i){
            uint4 a = *(const uint4*)(pr + 4*i);
            wr[4*i] = a.x; wr[4*i+1] = a.y; wr[4*i+2] = a.z; wr[4*i+3] = a.w;
            uint4 c = *(const uint4*)(pz + 4*i);
            wz[4*i] = c.x; wz[4*i+1] = c.y; wz[4*i+2] = c.z; wz[4*i+3] = c.w;
            uint4 d = *(const uint4*)(pn + 4*i);
            wn[4*i] = d.x; wn[4*i+1] = d.y; wn[4*i+2] = d.z; wn[4*i+3] = d.w;
        }
    }
    #pragma unroll
    for (int i = 0; i < 32; ++i)
        asm volatile("" : "+v"(wr[i]), "+v"(wz[i]), "+v"(wn[i]));

    const float br  = bih1[l]      + bhh1[l];
    const float bz  = bih1[64+l]   + bhh1[64+l];
    const float bxn = bih1[128+l];
    const float bhn = bhh1[128+l];
    float hreg = 0.f;
    const size_t rb = (size_t)b * S_;
    const _Float16* x0 = xgh + rb*192;
    _Float16 xra = x0[l],     xza = x0[64+l],     xna = x0[128+l];
    _Float16 xrb = x0[192+l], xzb = x0[192+64+l], xnb = x0[192+128+l];
    wsync();

    #pragma unroll 1
    for (int t = 0; t < S_; ++t){
        float xr = (float)xra, xz = (float)xza, xn = (float)xna;
        xra = xrb; xza = xzb; xna = xnb;
        {   int tn = (t + 2 < S_) ? t + 2 : S_ - 1;
            const _Float16* q = xgh + (rb + tn)*192;
            xrb = q[l]; xzb = q[64+l]; xnb = q[128+l]; }
        float ar0=0,az0=0,an0=0,ar1=0,az1=0,an1=0;
        #pragma unroll
        for (int k = 0; k < 8; ++k){
            uint4 hv = *(const uint4*)(HP + 4*k);
            float& ar = (k & 1) ? ar1 : ar0;
            float& az = (k & 1) ? az1 : az0;
            float& an = (k & 1) ? an1 : an0;
            ar = dot2h(hv.x, wr[4*k],   ar); ar = dot2h(hv.y, wr[4*k+1], ar);
            ar = dot2h(hv.z, wr[4*k+2], ar); ar = dot2h(hv.w, wr[4*k+3], ar);
            az = dot2h(hv.x, wz[4*k],   az); az = dot2h(hv.y, wz[4*k+1], az);
            az = dot2h(hv.z, wz[4*k+2], az); az = dot2h(hv.w, wz[4*k+3], az);
            an = dot2h(hv.x, wn[4*k],   an); an = dot2h(hv.y, wn[4*k+1], an);
            an = dot2h(hv.z, wn[4*k+2], an); an = dot2h(hv.w, wn[4*k+3], an);
        }
        float rg = fast_sigmoid(xr + ar0 + ar1 + br);
        float zg = fast_sigmoid(xz + az0 + az1 + bz);
        float ng = fast_tanh(xn + bxn + rg*(an0 + an1 + bhn));
        hreg = (1.f - zg)*ng + zg*hreg;
        float hp2 = __shfl_xor(hreg, 1);
        if (!(l & 1)) HP[l >> 1] = pack_h2f(hreg, hp2);
        wsync();
    }
    float hf0v = hf0g[(size_t)b*64 + l];
    float part = hf0v * Wpred[l] + hreg * Wpred[64 + l];
    #pragma unroll
    for (int s = 32; s >= 1; s >>= 1) part += __shfl_xor(part, s);
    if (l == 0) outp[b] = fast_tanh(part + bpred[0]);
}

// ---------- launcher ----------
extern "C" void kernel_launch(void* const* d_in, const int* in_sizes, int n_in,
                              void* d_out, int out_size, void* d_ws, size_t ws_size,
                              hipStream_t stream) {
    (void)in_sizes; (void)n_in; (void)out_size; (void)ws_size;
    const float* station_nodes    = (const float*)d_in[1];
    const float* station_features = (const float*)d_in[2];
    const int*   station_emb      = (const int*)d_in[3];
    const float* e0 = (const float*)d_in[4];
    const float* e1 = (const float*)d_in[5];
    const float* e2 = (const float*)d_in[6];
    const float* e3 = (const float*)d_in[7];
    const float* e4 = (const float*)d_in[8];
    const float* W_nodes = (const float*)d_in[9];
    const float* b_nodes = (const float*)d_in[10];
    const float* W_attn  = (const float*)d_in[11];
    const float* W_d1 = (const float*)d_in[13];
    const float* b_d1 = (const float*)d_in[14];
    const float* W_d2 = (const float*)d_in[15];
    const float* b_d2 = (const float*)d_in[16];
    const float* Wih0 = (const float*)d_in[17];
    const float* Whh0 = (const float*)d_in[18];
    const float* bih0 = (const float*)d_in[19];
    const float* bhh0 = (const float*)d_in[20];
    const float* Wih1 = (const float*)d_in[21];
    const float* Whh1 = (const float*)d_in[22];
    const float* bih1 = (const float*)d_in[23];
    const float* bhh1 = (const float*)d_in[24];
    const float* W_pred = (const float*)d_in[25];
    const float* b_pred = (const float*)d_in[26];
    float* outp = (float*)d_out;

    char* ws = (char*)d_ws;
    float*    attnW  = (float*)ws;                        // 512 KiB
    float*    hf0    = (float*)(ws + (1u<<19));           // 512 KiB
    unsigned* out0pk = (unsigned*)(ws + (1u<<20));        // B*S*32 u32 = 44 MB
    _Float16* xg16   = (_Float16*)(ws + (48u<<20));       // B*S*192 f16 = 132 MB
    const _Float16* xgh = (const _Float16*)xg16;

    nbst_attn<<<dim3(512), dim3(256), 0, stream>>>(station_nodes, W_nodes, b_nodes, W_attn, attnW);
    nbst_mlpxg0<<<dim3(768), dim3(256), 0, stream>>>(
        station_features, station_emb, e0, e1, e2, e3, e4,
        W_d1, b_d1, W_d2, b_d2, Wih0, attnW, xg16);
    nbst_rec0l<<<dim3(512), dim3(256), 0, stream>>>(xgh, Whh0, bih0, bhh0, out0pk, hf0);
    nbst_xg1<<<dim3(1024), dim3(256), 0, stream>>>(out0pk, Wih1, xg16);
    nbst_rec1l<<<dim3(512), dim3(256), 0, stream>>>(xgh, Whh1, bih1, bhh1, hf0, W_pred, b_pred, outp);
}